// Round 2
// baseline (1141.619 us; speedup 1.0000x reference)
//
#include <hip/hip_runtime.h>
#include <hip/hip_cooperative_groups.h>

namespace cg = cooperative_groups;

typedef __attribute__((ext_vector_type(8))) short short8;
typedef __attribute__((ext_vector_type(4))) float floatx4;

#define GLOBAL_AS __attribute__((address_space(1)))
#define LDS_AS __attribute__((address_space(3)))

__device__ __forceinline__ void gload_lds16(const void* g, void* l) {
  __builtin_amdgcn_global_load_lds((const GLOBAL_AS unsigned int*)g,
                                   (LDS_AS unsigned int*)l, 16, 0, 0);
}

__device__ __forceinline__ unsigned short rnbf(float f) {
  unsigned int v = __builtin_bit_cast(unsigned int, f);
  return (unsigned short)((v + 0x7fff + ((v >> 16) & 1)) >> 16);
}
__device__ __forceinline__ float bflo(unsigned int u) {
  return __builtin_bit_cast(float, u << 16);
}
__device__ __forceinline__ float bfhi(unsigned int u) {
  return __builtin_bit_cast(float, u & 0xffff0000u);
}

// ================= bf16 MFMA GEMM: C[M,N] = A[M,K] @ Bt[N,K]^T ==============
// 128x128 tile, BK=64, 256 thr = 4 waves in 2x2, each wave 64x64 (4x4 MFMA).
// XOR chunk swizzle staging (unchanged). NEW: bijective XCD block swizzle
// (m204) so the col-blocks sharing an A-panel co-locate on one XCD's L2.
#define TM 128
#define TN 128
#define BKE 64

__global__ __launch_bounds__(256) void gemm_bf16(
    const unsigned short* __restrict__ A,   // [M,K] bf16
    const unsigned short* __restrict__ Bt,  // [N,K] bf16 (= B^T)
    unsigned short* __restrict__ C,         // [M,N] bf16
    int M, int N, int K) {
  __shared__ __align__(16) unsigned short As[TM * BKE];
  __shared__ __align__(16) unsigned short Bs[TN * BKE];

  const int tid  = threadIdx.x;
  const int wave = tid >> 6;
  const int lane = tid & 63;
  const int wm = wave >> 1, wn = wave & 1;
  const int l15 = lane & 15, quad = lane >> 4;

  // bijective XCD swizzle: each XCD gets a contiguous lid chunk
  const int nwg = gridDim.x * gridDim.y;
  const int bid = blockIdx.y * gridDim.x + blockIdx.x;
  const int q = nwg >> 3, r = nwg & 7;
  const int xcd = bid & 7, off = bid >> 3;
  const int lid = ((xcd < r) ? xcd * (q + 1) : r * (q + 1) + (xcd - r) * q) + off;
  const int bm = (lid / gridDim.x) * TM;
  const int bn = (lid % gridDim.x) * TN;

  floatx4 acc[4][4];
#pragma unroll
  for (int i = 0; i < 4; ++i)
#pragma unroll
    for (int j = 0; j < 4; ++j) acc[i][j] = (floatx4){0.f, 0.f, 0.f, 0.f};

  const unsigned short* aptr[4];
  const unsigned short* bptr[4];
  int ldsoff[4];
#pragma unroll
  for (int j = 0; j < 4; ++j) {
    int ci = (wave * 4 + j) * 64 + lane;   // chunk index in tile
    int rr = ci >> 3;                      // local row 0..127
    int cs = (ci & 7) ^ (rr & 7);          // swizzled source chunk
    int arow = bm + rr; if (arow >= M) arow = M - 1;  // clamp; stores guarded
    aptr[j] = A  + (size_t)arow * K + cs * 8;
    bptr[j] = Bt + (size_t)(bn + rr) * K + cs * 8;    // N % 128 == 0
    ldsoff[j] = (wave * 4 + j) * 64 * 8;   // ushort offset of chunk base
  }

  for (int k0 = 0; k0 < K; k0 += BKE) {
#pragma unroll
    for (int j = 0; j < 4; ++j) {
      gload_lds16(aptr[j] + k0, &As[ldsoff[j]]);
      gload_lds16(bptr[j] + k0, &Bs[ldsoff[j]]);
    }
    __syncthreads();   // drains vmcnt (global_load_lds) + lgkm
#pragma unroll
    for (int s = 0; s < 2; ++s) {
      short8 af[4], bf[4];
#pragma unroll
      for (int mt = 0; mt < 4; ++mt) {
        int mrow = wm * 64 + mt * 16 + l15;
        int sw = (s * 4 + quad) ^ (mrow & 7);
        af[mt] = *(const short8*)&As[(mrow * 8 + sw) * 8];
      }
#pragma unroll
      for (int nt = 0; nt < 4; ++nt) {
        int nrow = wn * 64 + nt * 16 + l15;
        int sw = (s * 4 + quad) ^ (nrow & 7);
        bf[nt] = *(const short8*)&Bs[(nrow * 8 + sw) * 8];
      }
#pragma unroll
      for (int mt = 0; mt < 4; ++mt)
#pragma unroll
        for (int nt = 0; nt < 4; ++nt)
          acc[mt][nt] = __builtin_amdgcn_mfma_f32_16x16x32_bf16(
              af[mt], bf[nt], acc[mt][nt], 0, 0, 0);
    }
    __syncthreads();
  }

  // epilogue: C/D layout col=lane&15, row=quad*4+i  (m89/m91-verified)
#pragma unroll
  for (int mt = 0; mt < 4; ++mt) {
#pragma unroll
    for (int nt = 0; nt < 4; ++nt) {
      const int col = bn + wn * 64 + nt * 16 + l15;
#pragma unroll
      for (int i = 0; i < 4; ++i) {
        const int row = bm + wm * 64 + mt * 16 + quad * 4 + i;
        if (row < M) C[(size_t)row * N + col] = rnbf(acc[mt][nt][i]);
      }
    }
  }
}

// ============ fused preprocessing: ONE cooperative kernel ===================
// Replaces memset + hist + scan + fill + cast + 2 transposes (7 dispatches).
// Grid = 1024 blocks x 256 thr (exactly 4 blocks/CU co-resident).
// P0: W1/W2 transposes + zero cursor
// P1: hist (blocks 0..511)         || cast half 1 (blocks 512..1023)
// P2: per-block local scan (49 el) -> rowptr temp + partials[b]
// P3: block 0 scans partials[1024] -> exclusive block prefix (in place)
// P4: apply prefix -> rowptr / cursor (= CSR start offsets)
// P5: fill es/ws (blocks 0..511)   || cast half 2 (blocks 512..1023)
#define NB 1024
#define NT 256

__global__ __launch_bounds__(256, 4) void prep_fused(
    const float* __restrict__ x, const float* __restrict__ W1,
    const float* __restrict__ W2, const int* __restrict__ src,
    const int* __restrict__ dst, const float* __restrict__ ew,
    unsigned short* __restrict__ xb, unsigned short* __restrict__ W1t,
    unsigned short* __restrict__ W2t, int* __restrict__ rowptr,
    int* __restrict__ cursor, int* __restrict__ es, float* __restrict__ ws,
    int* __restrict__ partials, int Nn, int E) {
  cg::grid_group grid = cg::this_grid();
  const int b = blockIdx.x, t = threadIdx.x;
  const int tx = t & 31, ty = t >> 5;
  __shared__ float tile[32][33];
  __shared__ int sred[8];

  // ---------------- P0: transposes + zero cursor ----------------
  if (b < 512) {            // W1 [1024][512] -> W1t [512][1024]; 16x32 tiles
    const int bx = (b & 15) * 32, by = (b >> 4) * 32;
#pragma unroll
    for (int j = 0; j < 4; ++j)
      tile[ty + j * 8][tx] = W1[(size_t)(by + ty + j * 8) * 512 + bx + tx];
    __syncthreads();
#pragma unroll
    for (int j = 0; j < 4; ++j)
      W1t[(size_t)(bx + ty + j * 8) * 1024 + by + tx] = rnbf(tile[tx][ty + j * 8]);
  } else if (b < 640) {     // W2 [512][256] -> W2t [256][512]; 8x16 tiles
    const int id = b - 512;
    const int bx = (id & 7) * 32, by = (id >> 3) * 32;
#pragma unroll
    for (int j = 0; j < 4; ++j)
      tile[ty + j * 8][tx] = W2[(size_t)(by + ty + j * 8) * 256 + bx + tx];
    __syncthreads();
#pragma unroll
    for (int j = 0; j < 4; ++j)
      W2t[(size_t)(bx + ty + j * 8) * 512 + by + tx] = rnbf(tile[tx][ty + j * 8]);
  } else if (b < 840) {     // zero cursor
    const int i = (b - 640) * NT + t;
    if (i < Nn) cursor[i] = 0;
  }
  grid.sync();

  // ---------------- P1: hist || cast half 1 ----------------
  const long long n4 = (long long)Nn * 1024 / 4;
  const long long half = n4 / 2;
  if (b < 512) {
    for (int e = b * NT + t; e < E; e += 512 * NT) atomicAdd(&cursor[dst[e]], 1);
  } else {
    for (long long i = (long long)(b - 512) * NT + t; i < half; i += 512LL * NT) {
      float4 v = ((const float4*)x)[i];
      ushort4 o;
      o.x = rnbf(v.x); o.y = rnbf(v.y); o.z = rnbf(v.z); o.w = rnbf(v.w);
      ((ushort4*)xb)[i] = o;
    }
  }
  grid.sync();

  // ---------------- P2: per-block local scan ----------------
  const int Cn = (Nn + NB - 1) / NB;   // 49
  if (t < 64) {
    const int idx = b * Cn + t;
    const int v = (t < Cn && idx < Nn) ? cursor[idx] : 0;
    int xs = v;
#pragma unroll
    for (int o = 1; o < 64; o <<= 1) {
      int y = __shfl_up(xs, o, 64);
      if (t >= o) xs += y;
    }
    if (t < Cn && idx < Nn) rowptr[idx + 1] = xs;   // local inclusive (temp)
    if (t == 63) partials[b] = xs;                  // block total
  }
  grid.sync();

  // ---------------- P3: block 0 scans partials[NB] ----------------
  if (b == 0) {
    const int p0 = partials[t * 4], p1 = partials[t * 4 + 1];
    const int p2 = partials[t * 4 + 2], p3 = partials[t * 4 + 3];
    const int ssum = p0 + p1 + p2 + p3;
    int xs = ssum;
    const int ln = t & 63, wv = t >> 6;
#pragma unroll
    for (int o = 1; o < 64; o <<= 1) {
      int y = __shfl_up(xs, o, 64);
      if (ln >= o) xs += y;
    }
    if (ln == 63) sred[wv] = xs;
    __syncthreads();
    int wpre = 0;
    for (int k = 0; k < wv; ++k) wpre += sred[k];
    const int exc = wpre + xs - ssum;   // exclusive base for this thread's 4
    partials[t * 4]     = exc;
    partials[t * 4 + 1] = exc + p0;
    partials[t * 4 + 2] = exc + p0 + p1;
    partials[t * 4 + 3] = exc + p0 + p1 + p2;
  }
  grid.sync();

  // ---------------- P4: apply prefix ----------------
  if (t < Cn) {
    const int idx = b * Cn + t;
    if (idx < Nn) {
      const int v = cursor[idx];
      const int inc = partials[b] + rowptr[idx + 1];
      rowptr[idx + 1] = inc;
      cursor[idx] = inc - v;            // CSR start offsets for fill
    }
  }
  if (b == 0 && t == 0) rowptr[0] = 0;
  grid.sync();

  // ---------------- P5: fill || cast half 2 ----------------
  if (b < 512) {
    for (int e = b * NT + t; e < E; e += 512 * NT) {
      const int pos = atomicAdd(&cursor[dst[e]], 1);
      es[pos] = src[e];
      ws[pos] = ew[e];
    }
  } else {
    for (long long i = half + (long long)(b - 512) * NT + t; i < n4;
         i += 512LL * NT) {
      float4 v = ((const float4*)x)[i];
      ushort4 o;
      o.x = rnbf(v.x); o.y = rnbf(v.y); o.z = rnbf(v.z); o.w = rnbf(v.w);
      ((ushort4*)xb)[i] = o;
    }
  }
}

// ------- gather layer1: bf16 S [Nn,512] -> bf16 out (bias+relu fused) -------
__global__ __launch_bounds__(256) void gather1_b2b(
    const unsigned short* __restrict__ S, const int* __restrict__ es,
    const float* __restrict__ ws, const int* __restrict__ rowptr,
    const float* __restrict__ bias, unsigned short* __restrict__ out, int Nn) {
  const int tn = threadIdx.x & 63;                 // 64 thr/node, 8 bf16 each
  const int node = blockIdx.x * 4 + (threadIdx.x >> 6);
  if (node >= Nn) return;
  const int f = tn << 3;
  float acc[8] = {};
  const int beg = rowptr[node], end = rowptr[node + 1];
  for (int b = beg; b < end; b += 64) {
    const int m = end - b;
    int   sv_l = 0;
    float w_l  = 0.f;
    if (tn < m) { sv_l = es[b + tn]; w_l = ws[b + tn]; }
    const int cnt = (m < 64) ? m : 64;
    for (int i = 0; i < cnt; ++i) {
      const int   sv = __shfl(sv_l, i, 64);
      const float ww = __shfl(w_l, i, 64);
      const uint4 u = *(const uint4*)(S + (size_t)sv * 512 + f);
      acc[0] = fmaf(bflo(u.x), ww, acc[0]);
      acc[1] = fmaf(bfhi(u.x), ww, acc[1]);
      acc[2] = fmaf(bflo(u.y), ww, acc[2]);
      acc[3] = fmaf(bfhi(u.y), ww, acc[3]);
      acc[4] = fmaf(bflo(u.z), ww, acc[4]);
      acc[5] = fmaf(bfhi(u.z), ww, acc[5]);
      acc[6] = fmaf(bflo(u.w), ww, acc[6]);
      acc[7] = fmaf(bfhi(u.w), ww, acc[7]);
    }
  }
  float r[8];
#pragma unroll
  for (int j = 0; j < 8; ++j) r[j] = fmaxf(acc[j] + bias[f + j], 0.f);
  uint4 o;
  o.x = (unsigned int)rnbf(r[0]) | ((unsigned int)rnbf(r[1]) << 16);
  o.y = (unsigned int)rnbf(r[2]) | ((unsigned int)rnbf(r[3]) << 16);
  o.z = (unsigned int)rnbf(r[4]) | ((unsigned int)rnbf(r[5]) << 16);
  o.w = (unsigned int)rnbf(r[6]) | ((unsigned int)rnbf(r[7]) << 16);
  *(uint4*)(out + (size_t)node * 512 + f) = o;
}

// ------- gather layer2: bf16 S [Nn,256] -> f32 out (bias+relu fused) --------
__global__ __launch_bounds__(256) void gather2_b2f(
    const unsigned short* __restrict__ S, const int* __restrict__ es,
    const float* __restrict__ ws, const int* __restrict__ rowptr,
    const float* __restrict__ bias, float* __restrict__ out, int Nn) {
  const int tn = threadIdx.x & 31;                 // 32 thr/node, 8 bf16 each
  const int node = blockIdx.x * 8 + (threadIdx.x >> 5);
  if (node >= Nn) return;
  const int f = tn << 3;
  float acc[8] = {};
  const int beg = rowptr[node], end = rowptr[node + 1];
  for (int b = beg; b < end; b += 32) {
    const int m = end - b;
    int   sv_l = 0;
    float w_l  = 0.f;
    if (tn < m) { sv_l = es[b + tn]; w_l = ws[b + tn]; }
    const int cnt = (m < 32) ? m : 32;
    for (int i = 0; i < cnt; ++i) {
      const int   sv = __shfl(sv_l, i, 32);
      const float ww = __shfl(w_l, i, 32);
      const uint4 u = *(const uint4*)(S + (size_t)sv * 256 + f);
      acc[0] = fmaf(bflo(u.x), ww, acc[0]);
      acc[1] = fmaf(bfhi(u.x), ww, acc[1]);
      acc[2] = fmaf(bflo(u.y), ww, acc[2]);
      acc[3] = fmaf(bfhi(u.y), ww, acc[3]);
      acc[4] = fmaf(bflo(u.z), ww, acc[4]);
      acc[5] = fmaf(bfhi(u.z), ww, acc[5]);
      acc[6] = fmaf(bflo(u.w), ww, acc[6]);
      acc[7] = fmaf(bfhi(u.w), ww, acc[7]);
    }
  }
  float4 o1, o2;
  o1.x = fmaxf(acc[0] + bias[f + 0], 0.f);
  o1.y = fmaxf(acc[1] + bias[f + 1], 0.f);
  o1.z = fmaxf(acc[2] + bias[f + 2], 0.f);
  o1.w = fmaxf(acc[3] + bias[f + 3], 0.f);
  o2.x = fmaxf(acc[4] + bias[f + 4], 0.f);
  o2.y = fmaxf(acc[5] + bias[f + 5], 0.f);
  o2.z = fmaxf(acc[6] + bias[f + 6], 0.f);
  o2.w = fmaxf(acc[7] + bias[f + 7], 0.f);
  *(float4*)(out + (size_t)node * 256 + f) = o1;
  *(float4*)(out + (size_t)node * 256 + f + 4) = o2;
}

// ============================================================================
extern "C" void kernel_launch(void* const* d_in, const int* in_sizes, int n_in,
                              void* d_out, int out_size, void* d_ws, size_t ws_size,
                              hipStream_t stream) {
  const float* x  = (const float*)d_in[0];
  const int*   ei = (const int*)d_in[1];
  const float* ew = (const float*)d_in[2];
  const float* W1 = (const float*)d_in[3];
  const float* b1 = (const float*)d_in[4];
  const float* W2 = (const float*)d_in[5];
  const float* b2 = (const float*)d_in[6];

  const int D_IN = 1024, D_HID = 512, D_LAT = 256;
  const int Nn = in_sizes[0] / D_IN;   // 50000
  const int E  = in_sizes[2];          // 400000
  const int* src  = ei;
  const int* dstp = ei + E;

  // ws layout (region A aliases xb->hb, region B aliases s1->s2):
  //  A: [0, Nn*1024*2)            xb bf16; later hb bf16 (Nn*512*2 <= that)
  //  B: [A, A + Nn*512*2)         s1 bf16; later s2 bf16 (Nn*256*2 <= that)
  //  C: W1t, W2t, rowptr, cursor, es, ws, partials        (~5 MB)
  char* base = (char*)d_ws;
  const size_t szA = (size_t)Nn * D_IN * 2;
  const size_t szB = (size_t)Nn * D_HID * 2;
  unsigned short* xb  = (unsigned short*)base;
  unsigned short* hb  = (unsigned short*)base;             // alias, xb dead
  unsigned short* s1  = (unsigned short*)(base + szA);
  unsigned short* s2  = (unsigned short*)(base + szA);     // alias, s1 dead
  char* tail = base + szA + szB;
  unsigned short* W1t = (unsigned short*)tail;
  unsigned short* W2t = W1t + (size_t)D_IN * D_HID;
  int*   rowptr   = (int*)(W2t + (size_t)D_HID * D_LAT);
  int*   cursor   = rowptr + (Nn + 1);
  int*   es       = cursor + Nn;
  float* wsrt     = (float*)(es + E);
  int*   partials = (int*)(wsrt + E);

  // ---- fused preprocessing (cooperative: CSR build + casts + transposes) ----
  int Nn_a = Nn, E_a = E;
  void* args[] = {(void*)&x,      (void*)&W1,   (void*)&W2,   (void*)&src,
                  (void*)&dstp,   (void*)&ew,   (void*)&xb,   (void*)&W1t,
                  (void*)&W2t,    (void*)&rowptr, (void*)&cursor, (void*)&es,
                  (void*)&wsrt,   (void*)&partials, (void*)&Nn_a, (void*)&E_a};
  hipLaunchCooperativeKernel((const void*)prep_fused, dim3(NB), dim3(NT), args,
                             0u, stream);

  // ---- layer 1 ----
  dim3 g1(D_HID / TN, (Nn + TM - 1) / TM);
  gemm_bf16<<<g1, 256, 0, stream>>>(xb, W1t, s1, Nn, D_HID, D_IN);
  gather1_b2b<<<(Nn + 3) / 4, 256, 0, stream>>>(
      s1, es, wsrt, rowptr, b1, hb, Nn);

  // ---- layer 2 ----
  dim3 g2(D_LAT / TN, (Nn + TM - 1) / TM);
  gemm_bf16<<<g2, 256, 0, stream>>>(hb, W2t, s2, Nn, D_LAT, D_HID);
  gather2_b2f<<<(Nn + 7) / 8, 256, 0, stream>>>(
      s2, es, wsrt, rowptr, b2, (float*)d_out, Nn);
}

// Round 3
// 686.217 us; speedup vs baseline: 1.6636x; 1.6636x over previous
//
#include <hip/hip_runtime.h>

typedef __attribute__((ext_vector_type(8))) short short8;
typedef __attribute__((ext_vector_type(4))) float floatx4;

#define GLOBAL_AS __attribute__((address_space(1)))
#define LDS_AS __attribute__((address_space(3)))

__device__ __forceinline__ void gload_lds16(const void* g, void* l) {
  __builtin_amdgcn_global_load_lds((const GLOBAL_AS unsigned int*)g,
                                   (LDS_AS unsigned int*)l, 16, 0, 0);
}

__device__ __forceinline__ unsigned short rnbf(float f) {
  unsigned int v = __builtin_bit_cast(unsigned int, f);
  return (unsigned short)((v + 0x7fff + ((v >> 16) & 1)) >> 16);
}
__device__ __forceinline__ float bflo(unsigned int u) {
  return __builtin_bit_cast(float, u << 16);
}
__device__ __forceinline__ float bfhi(unsigned int u) {
  return __builtin_bit_cast(float, u & 0xffff0000u);
}

// ================= bf16 MFMA GEMM: C[M,N] = A[M,K] @ Bt[N,K]^T ==============
// 128x128 tile, BK=64, 256 thr = 4 waves in 2x2, each wave 64x64 (4x4 MFMA).
// XOR chunk swizzle staging + bijective XCD block swizzle (m204): 4 (or 2)
// consecutive lids share one A-panel and land on one XCD's L2.
#define TM 128
#define TN 128
#define BKE 64

__global__ __launch_bounds__(256) void gemm_bf16(
    const unsigned short* __restrict__ A,   // [M,K] bf16
    const unsigned short* __restrict__ Bt,  // [N,K] bf16 (= B^T)
    unsigned short* __restrict__ C,         // [M,N] bf16
    int M, int N, int K) {
  __shared__ __align__(16) unsigned short As[TM * BKE];
  __shared__ __align__(16) unsigned short Bs[TN * BKE];

  const int tid  = threadIdx.x;
  const int wave = tid >> 6;
  const int lane = tid & 63;
  const int wm = wave >> 1, wn = wave & 1;
  const int l15 = lane & 15, quad = lane >> 4;

  // bijective XCD swizzle
  const int nwg = gridDim.x * gridDim.y;
  const int bid = blockIdx.y * gridDim.x + blockIdx.x;
  const int q = nwg >> 3, r = nwg & 7;
  const int xcd = bid & 7, off = bid >> 3;
  const int lid = ((xcd < r) ? xcd * (q + 1) : r * (q + 1) + (xcd - r) * q) + off;
  const int bm = (lid / gridDim.x) * TM;
  const int bn = (lid % gridDim.x) * TN;

  floatx4 acc[4][4];
#pragma unroll
  for (int i = 0; i < 4; ++i)
#pragma unroll
    for (int j = 0; j < 4; ++j) acc[i][j] = (floatx4){0.f, 0.f, 0.f, 0.f};

  const unsigned short* aptr[4];
  const unsigned short* bptr[4];
  int ldsoff[4];
#pragma unroll
  for (int j = 0; j < 4; ++j) {
    int ci = (wave * 4 + j) * 64 + lane;   // chunk index in tile
    int rr = ci >> 3;                      // local row 0..127
    int cs = (ci & 7) ^ (rr & 7);          // swizzled source chunk
    int arow = bm + rr; if (arow >= M) arow = M - 1;  // clamp; stores guarded
    aptr[j] = A  + (size_t)arow * K + cs * 8;
    bptr[j] = Bt + (size_t)(bn + rr) * K + cs * 8;    // N % 128 == 0
    ldsoff[j] = (wave * 4 + j) * 64 * 8;   // ushort offset of chunk base
  }

  for (int k0 = 0; k0 < K; k0 += BKE) {
#pragma unroll
    for (int j = 0; j < 4; ++j) {
      gload_lds16(aptr[j] + k0, &As[ldsoff[j]]);
      gload_lds16(bptr[j] + k0, &Bs[ldsoff[j]]);
    }
    __syncthreads();   // drains vmcnt (global_load_lds) + lgkm
#pragma unroll
    for (int s = 0; s < 2; ++s) {
      short8 af[4], bf[4];
#pragma unroll
      for (int mt = 0; mt < 4; ++mt) {
        int mrow = wm * 64 + mt * 16 + l15;
        int sw = (s * 4 + quad) ^ (mrow & 7);
        af[mt] = *(const short8*)&As[(mrow * 8 + sw) * 8];
      }
#pragma unroll
      for (int nt = 0; nt < 4; ++nt) {
        int nrow = wn * 64 + nt * 16 + l15;
        int sw = (s * 4 + quad) ^ (nrow & 7);
        bf[nt] = *(const short8*)&Bs[(nrow * 8 + sw) * 8];
      }
#pragma unroll
      for (int mt = 0; mt < 4; ++mt)
#pragma unroll
        for (int nt = 0; nt < 4; ++nt)
          acc[mt][nt] = __builtin_amdgcn_mfma_f32_16x16x32_bf16(
              af[mt], bf[nt], acc[mt][nt], 0, 0, 0);
    }
    __syncthreads();
  }

  // epilogue: C/D layout col=lane&15, row=quad*4+i  (m89/m91-verified)
#pragma unroll
  for (int mt = 0; mt < 4; ++mt) {
#pragma unroll
    for (int nt = 0; nt < 4; ++nt) {
      const int col = bn + wn * 64 + nt * 16 + l15;
#pragma unroll
      for (int i = 0; i < 4; ++i) {
        const int row = bm + wm * 64 + mt * 16 + quad * 4 + i;
        if (row < M) C[(size_t)row * N + col] = rnbf(acc[mt][nt][i]);
      }
    }
  }
}

// ====== fused independent preprocessing (NO grid.sync — one launch) =========
// blocks [0,1024): cast x f32->bf16 (long pole, dispatched first)
// blocks [1024,1536): hist of dst into cursor (atomic-bound, overlaps cast)
// blocks [1536,2048): W1 [1024][512] -> W1t [512][1024] transpose-cast
// blocks [2048,2176): W2 [512][256]  -> W2t [256][512]  transpose-cast
#define PRE_CAST_B 1024
#define PRE_HIST_B 512
#define PRE_W1_B 512
#define PRE_W2_B 128

__global__ __launch_bounds__(256) void pre_fused(
    const float* __restrict__ x, unsigned short* __restrict__ xb, long long n4,
    const int* __restrict__ dst, int* __restrict__ cursor, int E,
    const float* __restrict__ W1, unsigned short* __restrict__ W1t,
    const float* __restrict__ W2, unsigned short* __restrict__ W2t) {
  __shared__ float tile[32][33];
  const int b = blockIdx.x, t = threadIdx.x;
  if (b < PRE_CAST_B) {
    for (long long i = (long long)b * 256 + t; i < n4;
         i += (long long)PRE_CAST_B * 256) {
      float4 v = ((const float4*)x)[i];
      ushort4 o;
      o.x = rnbf(v.x); o.y = rnbf(v.y); o.z = rnbf(v.z); o.w = rnbf(v.w);
      ((ushort4*)xb)[i] = o;
    }
  } else if (b < PRE_CAST_B + PRE_HIST_B) {
    const int bb = b - PRE_CAST_B;
    for (int e = bb * 256 + t; e < E; e += PRE_HIST_B * 256)
      atomicAdd(&cursor[dst[e]], 1);
  } else if (b < PRE_CAST_B + PRE_HIST_B + PRE_W1_B) {
    const int id = b - (PRE_CAST_B + PRE_HIST_B);
    const int bx = (id & 15) * 32, by = (id >> 4) * 32;   // N=512, K=1024
    const int tx = t & 31, ty = t >> 5;
#pragma unroll
    for (int j = 0; j < 4; ++j)
      tile[ty + j * 8][tx] = W1[(size_t)(by + ty + j * 8) * 512 + bx + tx];
    __syncthreads();
#pragma unroll
    for (int j = 0; j < 4; ++j)
      W1t[(size_t)(bx + ty + j * 8) * 1024 + by + tx] = rnbf(tile[tx][ty + j * 8]);
  } else {
    const int id = b - (PRE_CAST_B + PRE_HIST_B + PRE_W1_B);
    const int bx = (id & 7) * 32, by = (id >> 3) * 32;    // N=256, K=512
    const int tx = t & 31, ty = t >> 5;
#pragma unroll
    for (int j = 0; j < 4; ++j)
      tile[ty + j * 8][tx] = W2[(size_t)(by + ty + j * 8) * 256 + bx + tx];
    __syncthreads();
#pragma unroll
    for (int j = 0; j < 4; ++j)
      W2t[(size_t)(bx + ty + j * 8) * 512 + by + tx] = rnbf(tile[tx][ty + j * 8]);
  }
}

// ====== single-block scan: per-thread serial segment + one wave/LDS scan ====
// 1024 threads x SEG=ceil(n/1024) contiguous elems each; 2 barriers total.
// In: cursor[i] = counts. Out: rowptr[0..n] (inclusive prefix shifted),
//                            cursor[i] = exclusive start offsets (for fill).
__global__ __launch_bounds__(1024) void scan_one(
    int* cursor, int* __restrict__ rowptr, int n) {
  __shared__ int wsum[16];
  const int t = threadIdx.x, ln = t & 63, wv = t >> 6;
  const int SEG = (n + 1023) >> 10;
  const int beg = t * SEG;
  int s = 0;
  for (int k = 0; k < SEG; ++k) {
    const int i = beg + k;
    if (i < n) s += cursor[i];
  }
  int xinc = s;
#pragma unroll
  for (int o = 1; o < 64; o <<= 1) {
    int y = __shfl_up(xinc, o, 64);
    if (ln >= o) xinc += y;
  }
  if (ln == 63) wsum[wv] = xinc;
  __syncthreads();
  if (t < 16) {
    int v = wsum[t];
#pragma unroll
    for (int o = 1; o < 16; o <<= 1) {
      int y = __shfl_up(v, o, 64);
      if (t >= o) v += y;
    }
    wsum[t] = v;
  }
  __syncthreads();
  int run = ((wv > 0) ? wsum[wv - 1] : 0) + xinc - s;   // exclusive base
  for (int k = 0; k < SEG; ++k) {
    const int i = beg + k;
    if (i < n) {
      const int v = cursor[i];
      cursor[i] = run;            // exclusive offset (fill start)
      rowptr[i + 1] = run + v;    // inclusive prefix
      run += v;
    }
  }
  if (t == 0) rowptr[0] = 0;
}

// scatter reordered (src, w) directly -> no eid indirection in gathers
__global__ __launch_bounds__(256) void fill_csr(
    const int* __restrict__ dst, const int* __restrict__ src,
    const float* __restrict__ w, int* __restrict__ cursor,
    int* __restrict__ es, float* __restrict__ ws, int E) {
  int e = blockIdx.x * blockDim.x + threadIdx.x;
  if (e < E) {
    int pos = atomicAdd(&cursor[dst[e]], 1);
    es[pos] = src[e];
    ws[pos] = w[e];
  }
}

// ------- gather layer1: bf16 S [Nn,512] -> bf16 out (bias+relu fused) -------
__global__ __launch_bounds__(256) void gather1_b2b(
    const unsigned short* __restrict__ S, const int* __restrict__ es,
    const float* __restrict__ ws, const int* __restrict__ rowptr,
    const float* __restrict__ bias, unsigned short* __restrict__ out, int Nn) {
  const int tn = threadIdx.x & 63;                 // 64 thr/node, 8 bf16 each
  const int node = blockIdx.x * 4 + (threadIdx.x >> 6);
  if (node >= Nn) return;
  const int f = tn << 3;
  float acc[8] = {};
  const int beg = rowptr[node], end = rowptr[node + 1];
  for (int b = beg; b < end; b += 64) {
    const int m = end - b;
    int   sv_l = 0;
    float w_l  = 0.f;
    if (tn < m) { sv_l = es[b + tn]; w_l = ws[b + tn]; }
    const int cnt = (m < 64) ? m : 64;
    for (int i = 0; i < cnt; ++i) {
      const int   sv = __shfl(sv_l, i, 64);
      const float ww = __shfl(w_l, i, 64);
      const uint4 u = *(const uint4*)(S + (size_t)sv * 512 + f);
      acc[0] = fmaf(bflo(u.x), ww, acc[0]);
      acc[1] = fmaf(bfhi(u.x), ww, acc[1]);
      acc[2] = fmaf(bflo(u.y), ww, acc[2]);
      acc[3] = fmaf(bfhi(u.y), ww, acc[3]);
      acc[4] = fmaf(bflo(u.z), ww, acc[4]);
      acc[5] = fmaf(bfhi(u.z), ww, acc[5]);
      acc[6] = fmaf(bflo(u.w), ww, acc[6]);
      acc[7] = fmaf(bfhi(u.w), ww, acc[7]);
    }
  }
  float r[8];
#pragma unroll
  for (int j = 0; j < 8; ++j) r[j] = fmaxf(acc[j] + bias[f + j], 0.f);
  uint4 o;
  o.x = (unsigned int)rnbf(r[0]) | ((unsigned int)rnbf(r[1]) << 16);
  o.y = (unsigned int)rnbf(r[2]) | ((unsigned int)rnbf(r[3]) << 16);
  o.z = (unsigned int)rnbf(r[4]) | ((unsigned int)rnbf(r[5]) << 16);
  o.w = (unsigned int)rnbf(r[6]) | ((unsigned int)rnbf(r[7]) << 16);
  *(uint4*)(out + (size_t)node * 512 + f) = o;
}

// ------- gather layer2: bf16 S [Nn,256] -> f32 out (bias+relu fused) --------
__global__ __launch_bounds__(256) void gather2_b2f(
    const unsigned short* __restrict__ S, const int* __restrict__ es,
    const float* __restrict__ ws, const int* __restrict__ rowptr,
    const float* __restrict__ bias, float* __restrict__ out, int Nn) {
  const int tn = threadIdx.x & 31;                 // 32 thr/node, 8 bf16 each
  const int node = blockIdx.x * 8 + (threadIdx.x >> 5);
  if (node >= Nn) return;
  const int f = tn << 3;
  float acc[8] = {};
  const int beg = rowptr[node], end = rowptr[node + 1];
  for (int b = beg; b < end; b += 32) {
    const int m = end - b;
    int   sv_l = 0;
    float w_l  = 0.f;
    if (tn < m) { sv_l = es[b + tn]; w_l = ws[b + tn]; }
    const int cnt = (m < 32) ? m : 32;
    for (int i = 0; i < cnt; ++i) {
      const int   sv = __shfl(sv_l, i, 32);
      const float ww = __shfl(w_l, i, 32);
      const uint4 u = *(const uint4*)(S + (size_t)sv * 256 + f);
      acc[0] = fmaf(bflo(u.x), ww, acc[0]);
      acc[1] = fmaf(bfhi(u.x), ww, acc[1]);
      acc[2] = fmaf(bflo(u.y), ww, acc[2]);
      acc[3] = fmaf(bfhi(u.y), ww, acc[3]);
      acc[4] = fmaf(bflo(u.z), ww, acc[4]);
      acc[5] = fmaf(bfhi(u.z), ww, acc[5]);
      acc[6] = fmaf(bflo(u.w), ww, acc[6]);
      acc[7] = fmaf(bfhi(u.w), ww, acc[7]);
    }
  }
  float4 o1, o2;
  o1.x = fmaxf(acc[0] + bias[f + 0], 0.f);
  o1.y = fmaxf(acc[1] + bias[f + 1], 0.f);
  o1.z = fmaxf(acc[2] + bias[f + 2], 0.f);
  o1.w = fmaxf(acc[3] + bias[f + 3], 0.f);
  o2.x = fmaxf(acc[4] + bias[f + 4], 0.f);
  o2.y = fmaxf(acc[5] + bias[f + 5], 0.f);
  o2.z = fmaxf(acc[6] + bias[f + 6], 0.f);
  o2.w = fmaxf(acc[7] + bias[f + 7], 0.f);
  *(float4*)(out + (size_t)node * 256 + f) = o1;
  *(float4*)(out + (size_t)node * 256 + f + 4) = o2;
}

// ============================================================================
extern "C" void kernel_launch(void* const* d_in, const int* in_sizes, int n_in,
                              void* d_out, int out_size, void* d_ws, size_t ws_size,
                              hipStream_t stream) {
  const float* x  = (const float*)d_in[0];
  const int*   ei = (const int*)d_in[1];
  const float* ew = (const float*)d_in[2];
  const float* W1 = (const float*)d_in[3];
  const float* b1 = (const float*)d_in[4];
  const float* W2 = (const float*)d_in[5];
  const float* b2 = (const float*)d_in[6];

  const int D_IN = 1024, D_HID = 512, D_LAT = 256;
  const int Nn = in_sizes[0] / D_IN;   // 50000
  const int E  = in_sizes[2];          // 400000
  const int* src  = ei;
  const int* dstp = ei + E;

  // ws layout (region A aliases xb->hb, region B aliases s1->s2):
  //  A: [0, Nn*1024*2)            xb bf16; later hb bf16
  //  B: [A, A + Nn*512*2)         s1 bf16; later s2 bf16
  //  C: W1t, W2t, rowptr, cursor, es, ws                   (~5 MB)
  char* base = (char*)d_ws;
  const size_t szA = (size_t)Nn * D_IN * 2;
  const size_t szB = (size_t)Nn * D_HID * 2;
  unsigned short* xb  = (unsigned short*)base;
  unsigned short* hb  = (unsigned short*)base;             // alias, xb dead
  unsigned short* s1  = (unsigned short*)(base + szA);
  unsigned short* s2  = (unsigned short*)(base + szA);     // alias, s1 dead
  char* tail = base + szA + szB;
  unsigned short* W1t = (unsigned short*)tail;
  unsigned short* W2t = W1t + (size_t)D_IN * D_HID;
  int*   rowptr = (int*)(W2t + (size_t)D_HID * D_LAT);
  int*   cursor = rowptr + (Nn + 1);
  int*   es     = cursor + Nn;
  float* wsrt   = (float*)(es + E);

  long long n4 = (long long)Nn * D_IN / 4;

  // ---- preprocessing: memset -> fused{cast, hist, transposes} -> scan -> fill
  hipMemsetAsync(cursor, 0, (size_t)Nn * sizeof(int), stream);
  pre_fused<<<PRE_CAST_B + PRE_HIST_B + PRE_W1_B + PRE_W2_B, 256, 0, stream>>>(
      x, xb, n4, dstp, cursor, E, W1, W1t, W2, W2t);
  scan_one<<<1, 1024, 0, stream>>>(cursor, rowptr, Nn);
  fill_csr<<<(E + 255) / 256, 256, 0, stream>>>(dstp, src, ew, cursor, es, wsrt, E);

  // ---- layer 1 ----
  dim3 g1(D_HID / TN, (Nn + TM - 1) / TM);
  gemm_bf16<<<g1, 256, 0, stream>>>(xb, W1t, s1, Nn, D_HID, D_IN);
  gather1_b2b<<<(Nn + 3) / 4, 256, 0, stream>>>(
      s1, es, wsrt, rowptr, b1, hb, Nn);

  // ---- layer 2 ----
  dim3 g2(D_LAT / TN, (Nn + TM - 1) / TM);
  gemm_bf16<<<g2, 256, 0, stream>>>(hb, W2t, s2, Nn, D_LAT, D_HID);
  gather2_b2f<<<(Nn + 7) / 8, 256, 0, stream>>>(
      s2, es, wsrt, rowptr, b2, (float*)d_out, Nn);
}

// Round 4
// 572.852 us; speedup vs baseline: 1.9929x; 1.1979x over previous
//
#include <hip/hip_runtime.h>

typedef __attribute__((ext_vector_type(8))) short short8;
typedef __attribute__((ext_vector_type(4))) float floatx4;

#define GLOBAL_AS __attribute__((address_space(1)))
#define LDS_AS __attribute__((address_space(3)))

__device__ __forceinline__ void gload_lds16(const void* g, void* l) {
  __builtin_amdgcn_global_load_lds((const GLOBAL_AS unsigned int*)g,
                                   (LDS_AS unsigned int*)l, 16, 0, 0);
}

__device__ __forceinline__ unsigned short rnbf(float f) {
  unsigned int v = __builtin_bit_cast(unsigned int, f);
  return (unsigned short)((v + 0x7fff + ((v >> 16) & 1)) >> 16);
}
__device__ __forceinline__ float bflo(unsigned int u) {
  return __builtin_bit_cast(float, u << 16);
}
__device__ __forceinline__ float bfhi(unsigned int u) {
  return __builtin_bit_cast(float, u & 0xffff0000u);
}

// ================= bf16 MFMA GEMM: C[M,N] = A[M,K] @ Bt[N,K]^T ==============
// 128x128 tile, BK=64, 256 thr = 4 waves in 2x2, each wave 64x64 (4x4 MFMA).
// XOR chunk swizzle staging + bijective XCD block swizzle (m204).
#define TM 128
#define TN 128
#define BKE 64

__global__ __launch_bounds__(256) void gemm_bf16(
    const unsigned short* __restrict__ A,   // [M,K] bf16
    const unsigned short* __restrict__ Bt,  // [N,K] bf16 (= B^T)
    unsigned short* __restrict__ C,         // [M,N] bf16
    int M, int N, int K) {
  __shared__ __align__(16) unsigned short As[TM * BKE];
  __shared__ __align__(16) unsigned short Bs[TN * BKE];

  const int tid  = threadIdx.x;
  const int wave = tid >> 6;
  const int lane = tid & 63;
  const int wm = wave >> 1, wn = wave & 1;
  const int l15 = lane & 15, quad = lane >> 4;

  // bijective XCD swizzle
  const int nwg = gridDim.x * gridDim.y;
  const int bid = blockIdx.y * gridDim.x + blockIdx.x;
  const int q = nwg >> 3, r = nwg & 7;
  const int xcd = bid & 7, off = bid >> 3;
  const int lid = ((xcd < r) ? xcd * (q + 1) : r * (q + 1) + (xcd - r) * q) + off;
  const int bm = (lid / gridDim.x) * TM;
  const int bn = (lid % gridDim.x) * TN;

  floatx4 acc[4][4];
#pragma unroll
  for (int i = 0; i < 4; ++i)
#pragma unroll
    for (int j = 0; j < 4; ++j) acc[i][j] = (floatx4){0.f, 0.f, 0.f, 0.f};

  const unsigned short* aptr[4];
  const unsigned short* bptr[4];
  int ldsoff[4];
#pragma unroll
  for (int j = 0; j < 4; ++j) {
    int ci = (wave * 4 + j) * 64 + lane;   // chunk index in tile
    int rr = ci >> 3;                      // local row 0..127
    int cs = (ci & 7) ^ (rr & 7);          // swizzled source chunk
    int arow = bm + rr; if (arow >= M) arow = M - 1;  // clamp; stores guarded
    aptr[j] = A  + (size_t)arow * K + cs * 8;
    bptr[j] = Bt + (size_t)(bn + rr) * K + cs * 8;    // N % 128 == 0
    ldsoff[j] = (wave * 4 + j) * 64 * 8;   // ushort offset of chunk base
  }

  for (int k0 = 0; k0 < K; k0 += BKE) {
#pragma unroll
    for (int j = 0; j < 4; ++j) {
      gload_lds16(aptr[j] + k0, &As[ldsoff[j]]);
      gload_lds16(bptr[j] + k0, &Bs[ldsoff[j]]);
    }
    __syncthreads();   // drains vmcnt (global_load_lds) + lgkm
#pragma unroll
    for (int s = 0; s < 2; ++s) {
      short8 af[4], bf[4];
#pragma unroll
      for (int mt = 0; mt < 4; ++mt) {
        int mrow = wm * 64 + mt * 16 + l15;
        int sw = (s * 4 + quad) ^ (mrow & 7);
        af[mt] = *(const short8*)&As[(mrow * 8 + sw) * 8];
      }
#pragma unroll
      for (int nt = 0; nt < 4; ++nt) {
        int nrow = wn * 64 + nt * 16 + l15;
        int sw = (s * 4 + quad) ^ (nrow & 7);
        bf[nt] = *(const short8*)&Bs[(nrow * 8 + sw) * 8];
      }
#pragma unroll
      for (int mt = 0; mt < 4; ++mt)
#pragma unroll
        for (int nt = 0; nt < 4; ++nt)
          acc[mt][nt] = __builtin_amdgcn_mfma_f32_16x16x32_bf16(
              af[mt], bf[nt], acc[mt][nt], 0, 0, 0);
    }
    __syncthreads();
  }

  // epilogue: C/D layout col=lane&15, row=quad*4+i  (m89/m91-verified)
#pragma unroll
  for (int mt = 0; mt < 4; ++mt) {
#pragma unroll
    for (int nt = 0; nt < 4; ++nt) {
      const int col = bn + wn * 64 + nt * 16 + l15;
#pragma unroll
      for (int i = 0; i < 4; ++i) {
        const int row = bm + wm * 64 + mt * 16 + quad * 4 + i;
        if (row < M) C[(size_t)row * N + col] = rnbf(acc[mt][nt][i]);
      }
    }
  }
}

// ====== fused independent preprocessing (NO grid.sync — one launch) =========
// blocks [0,1024): cast x f32->bf16 (long pole)
// blocks [1024,1536): hist of dst into cursor (atomic-bound, overlaps cast)
// blocks [1536,2048): W1 transpose-cast;  [2048,2176): W2 transpose-cast
#define PRE_CAST_B 1024
#define PRE_HIST_B 512
#define PRE_W1_B 512
#define PRE_W2_B 128

__global__ __launch_bounds__(256) void pre_fused(
    const float* __restrict__ x, unsigned short* __restrict__ xb, long long n4,
    const int* __restrict__ dst, int* __restrict__ cursor, int E,
    const float* __restrict__ W1, unsigned short* __restrict__ W1t,
    const float* __restrict__ W2, unsigned short* __restrict__ W2t) {
  __shared__ float tile[32][33];
  const int b = blockIdx.x, t = threadIdx.x;
  if (b < PRE_CAST_B) {
    for (long long i = (long long)b * 256 + t; i < n4;
         i += (long long)PRE_CAST_B * 256) {
      float4 v = ((const float4*)x)[i];
      ushort4 o;
      o.x = rnbf(v.x); o.y = rnbf(v.y); o.z = rnbf(v.z); o.w = rnbf(v.w);
      ((ushort4*)xb)[i] = o;
    }
  } else if (b < PRE_CAST_B + PRE_HIST_B) {
    const int bb = b - PRE_CAST_B;
    for (int e = bb * 256 + t; e < E; e += PRE_HIST_B * 256)
      atomicAdd(&cursor[dst[e]], 1);
  } else if (b < PRE_CAST_B + PRE_HIST_B + PRE_W1_B) {
    const int id = b - (PRE_CAST_B + PRE_HIST_B);
    const int bx = (id & 15) * 32, by = (id >> 4) * 32;   // N=512, K=1024
    const int tx = t & 31, ty = t >> 5;
#pragma unroll
    for (int j = 0; j < 4; ++j)
      tile[ty + j * 8][tx] = W1[(size_t)(by + ty + j * 8) * 512 + bx + tx];
    __syncthreads();
#pragma unroll
    for (int j = 0; j < 4; ++j)
      W1t[(size_t)(bx + ty + j * 8) * 1024 + by + tx] = rnbf(tile[tx][ty + j * 8]);
  } else {
    const int id = b - (PRE_CAST_B + PRE_HIST_B + PRE_W1_B);
    const int bx = (id & 7) * 32, by = (id >> 3) * 32;    // N=256, K=512
    const int tx = t & 31, ty = t >> 5;
#pragma unroll
    for (int j = 0; j < 4; ++j)
      tile[ty + j * 8][tx] = W2[(size_t)(by + ty + j * 8) * 256 + bx + tx];
    __syncthreads();
#pragma unroll
    for (int j = 0; j < 4; ++j)
      W2t[(size_t)(bx + ty + j * 8) * 512 + by + tx] = rnbf(tile[tx][ty + j * 8]);
  }
}

// ====== parallel 3-phase scan (replaces 122 µs single-block scan_one) =======
// P1: 49 blocks x 256 thr x int4 -> block-local inclusive into rowptr temp,
//     block total into partials[b]. Coalesced 16B/lane loads.
__global__ __launch_bounds__(256) void scan_partial(
    const int* __restrict__ cursor, int* __restrict__ rowptr,
    int* __restrict__ partials, int n) {
  __shared__ int wsum[4];
  const int t = threadIdx.x, ln = t & 63, wv = t >> 6;
  const int base = blockIdx.x * 1024 + t * 4;
  int4 v = {0, 0, 0, 0};
  if (base + 3 < n) {
    v = *(const int4*)(cursor + base);
  } else {
    if (base + 0 < n) v.x = cursor[base + 0];
    if (base + 1 < n) v.y = cursor[base + 1];
    if (base + 2 < n) v.z = cursor[base + 2];
    if (base + 3 < n) v.w = cursor[base + 3];
  }
  const int s = v.x + v.y + v.z + v.w;
  int inc = s;
#pragma unroll
  for (int o = 1; o < 64; o <<= 1) {
    int y = __shfl_up(inc, o, 64);
    if (ln >= o) inc += y;
  }
  if (ln == 63) wsum[wv] = inc;
  __syncthreads();
  int wpre = 0;
#pragma unroll
  for (int k = 0; k < 4; ++k) wpre += (k < wv) ? wsum[k] : 0;
  const int exc = wpre + inc - s;          // block-local exclusive base
  if (base + 0 < n) rowptr[base + 1] = exc + v.x;
  if (base + 1 < n) rowptr[base + 2] = exc + v.x + v.y;
  if (base + 2 < n) rowptr[base + 3] = exc + v.x + v.y + v.z;
  if (base + 3 < n) rowptr[base + 4] = exc + s;
  if (t == 0) {
    // block total = sum of all wave sums (after barrier wsum is complete)
    partials[blockIdx.x] = wsum[0] + wsum[1] + wsum[2] + wsum[3];
  }
}

// P2: one wave scans the <=64 block totals in place -> exclusive prefixes.
__global__ __launch_bounds__(64) void scan_base(int* partials, int nb) {
  const int t = threadIdx.x;
  const int v = (t < nb) ? partials[t] : 0;
  int inc = v;
#pragma unroll
  for (int o = 1; o < 64; o <<= 1) {
    int y = __shfl_up(inc, o, 64);
    if (t >= o) inc += y;
  }
  if (t < nb) partials[t] = inc - v;       // exclusive
}

// P3: add block prefix; finalize rowptr and cursor (= CSR start offsets).
__global__ __launch_bounds__(256) void scan_apply(
    int* cursor, int* __restrict__ rowptr, const int* __restrict__ partials,
    int n) {
  const int base = blockIdx.x * 1024 + threadIdx.x * 4;
  const int p = partials[blockIdx.x];
#pragma unroll
  for (int k = 0; k < 4; ++k) {
    const int i = base + k;
    if (i < n) {
      const int cnt = cursor[i];
      const int inc = p + rowptr[i + 1];
      rowptr[i + 1] = inc;
      cursor[i] = inc - cnt;
    }
  }
  if (blockIdx.x == 0 && threadIdx.x == 0) rowptr[0] = 0;
}

// scatter reordered (src, w) directly -> no eid indirection in gathers
__global__ __launch_bounds__(256) void fill_csr(
    const int* __restrict__ dst, const int* __restrict__ src,
    const float* __restrict__ w, int* __restrict__ cursor,
    int* __restrict__ es, float* __restrict__ ws, int E) {
  int e = blockIdx.x * blockDim.x + threadIdx.x;
  if (e < E) {
    int pos = atomicAdd(&cursor[dst[e]], 1);
    es[pos] = src[e];
    ws[pos] = w[e];
  }
}

// ------- gather layer1: bf16 S [Nn,512] -> bf16 out (bias+relu fused) -------
__global__ __launch_bounds__(256) void gather1_b2b(
    const unsigned short* __restrict__ S, const int* __restrict__ es,
    const float* __restrict__ ws, const int* __restrict__ rowptr,
    const float* __restrict__ bias, unsigned short* __restrict__ out, int Nn) {
  const int tn = threadIdx.x & 63;                 // 64 thr/node, 8 bf16 each
  const int node = blockIdx.x * 4 + (threadIdx.x >> 6);
  if (node >= Nn) return;
  const int f = tn << 3;
  float acc[8] = {};
  const int beg = rowptr[node], end = rowptr[node + 1];
  for (int b = beg; b < end; b += 64) {
    const int m = end - b;
    int   sv_l = 0;
    float w_l  = 0.f;
    if (tn < m) { sv_l = es[b + tn]; w_l = ws[b + tn]; }
    const int cnt = (m < 64) ? m : 64;
    for (int i = 0; i < cnt; ++i) {
      const int   sv = __shfl(sv_l, i, 64);
      const float ww = __shfl(w_l, i, 64);
      const uint4 u = *(const uint4*)(S + (size_t)sv * 512 + f);
      acc[0] = fmaf(bflo(u.x), ww, acc[0]);
      acc[1] = fmaf(bfhi(u.x), ww, acc[1]);
      acc[2] = fmaf(bflo(u.y), ww, acc[2]);
      acc[3] = fmaf(bfhi(u.y), ww, acc[3]);
      acc[4] = fmaf(bflo(u.z), ww, acc[4]);
      acc[5] = fmaf(bfhi(u.z), ww, acc[5]);
      acc[6] = fmaf(bflo(u.w), ww, acc[6]);
      acc[7] = fmaf(bfhi(u.w), ww, acc[7]);
    }
  }
  float r[8];
#pragma unroll
  for (int j = 0; j < 8; ++j) r[j] = fmaxf(acc[j] + bias[f + j], 0.f);
  uint4 o;
  o.x = (unsigned int)rnbf(r[0]) | ((unsigned int)rnbf(r[1]) << 16);
  o.y = (unsigned int)rnbf(r[2]) | ((unsigned int)rnbf(r[3]) << 16);
  o.z = (unsigned int)rnbf(r[4]) | ((unsigned int)rnbf(r[5]) << 16);
  o.w = (unsigned int)rnbf(r[6]) | ((unsigned int)rnbf(r[7]) << 16);
  *(uint4*)(out + (size_t)node * 512 + f) = o;
}

// ------- gather layer2: bf16 S [Nn,256] -> f32 out (bias+relu fused) --------
__global__ __launch_bounds__(256) void gather2_b2f(
    const unsigned short* __restrict__ S, const int* __restrict__ es,
    const float* __restrict__ ws, const int* __restrict__ rowptr,
    const float* __restrict__ bias, float* __restrict__ out, int Nn) {
  const int tn = threadIdx.x & 31;                 // 32 thr/node, 8 bf16 each
  const int node = blockIdx.x * 8 + (threadIdx.x >> 5);
  if (node >= Nn) return;
  const int f = tn << 3;
  float acc[8] = {};
  const int beg = rowptr[node], end = rowptr[node + 1];
  for (int b = beg; b < end; b += 32) {
    const int m = end - b;
    int   sv_l = 0;
    float w_l  = 0.f;
    if (tn < m) { sv_l = es[b + tn]; w_l = ws[b + tn]; }
    const int cnt = (m < 32) ? m : 32;
    for (int i = 0; i < cnt; ++i) {
      const int   sv = __shfl(sv_l, i, 32);
      const float ww = __shfl(w_l, i, 32);
      const uint4 u = *(const uint4*)(S + (size_t)sv * 256 + f);
      acc[0] = fmaf(bflo(u.x), ww, acc[0]);
      acc[1] = fmaf(bfhi(u.x), ww, acc[1]);
      acc[2] = fmaf(bflo(u.y), ww, acc[2]);
      acc[3] = fmaf(bfhi(u.y), ww, acc[3]);
      acc[4] = fmaf(bflo(u.z), ww, acc[4]);
      acc[5] = fmaf(bfhi(u.z), ww, acc[5]);
      acc[6] = fmaf(bflo(u.w), ww, acc[6]);
      acc[7] = fmaf(bfhi(u.w), ww, acc[7]);
    }
  }
  float4 o1, o2;
  o1.x = fmaxf(acc[0] + bias[f + 0], 0.f);
  o1.y = fmaxf(acc[1] + bias[f + 1], 0.f);
  o1.z = fmaxf(acc[2] + bias[f + 2], 0.f);
  o1.w = fmaxf(acc[3] + bias[f + 3], 0.f);
  o2.x = fmaxf(acc[4] + bias[f + 4], 0.f);
  o2.y = fmaxf(acc[5] + bias[f + 5], 0.f);
  o2.z = fmaxf(acc[6] + bias[f + 6], 0.f);
  o2.w = fmaxf(acc[7] + bias[f + 7], 0.f);
  *(float4*)(out + (size_t)node * 256 + f) = o1;
  *(float4*)(out + (size_t)node * 256 + f + 4) = o2;
}

// ============================================================================
extern "C" void kernel_launch(void* const* d_in, const int* in_sizes, int n_in,
                              void* d_out, int out_size, void* d_ws, size_t ws_size,
                              hipStream_t stream) {
  const float* x  = (const float*)d_in[0];
  const int*   ei = (const int*)d_in[1];
  const float* ew = (const float*)d_in[2];
  const float* W1 = (const float*)d_in[3];
  const float* b1 = (const float*)d_in[4];
  const float* W2 = (const float*)d_in[5];
  const float* b2 = (const float*)d_in[6];

  const int D_IN = 1024, D_HID = 512, D_LAT = 256;
  const int Nn = in_sizes[0] / D_IN;   // 50000
  const int E  = in_sizes[2];          // 400000
  const int* src  = ei;
  const int* dstp = ei + E;

  // ws layout (region A aliases xb->hb, region B aliases s1->s2):
  //  A: [0, Nn*1024*2)            xb bf16; later hb bf16
  //  B: [A, A + Nn*512*2)         s1 bf16; later s2 bf16
  //  C: W1t, W2t, rowptr, cursor, es, ws, partials         (~5 MB)
  char* base = (char*)d_ws;
  const size_t szA = (size_t)Nn * D_IN * 2;
  const size_t szB = (size_t)Nn * D_HID * 2;
  unsigned short* xb  = (unsigned short*)base;
  unsigned short* hb  = (unsigned short*)base;             // alias, xb dead
  unsigned short* s1  = (unsigned short*)(base + szA);
  unsigned short* s2  = (unsigned short*)(base + szA);     // alias, s1 dead
  char* tail = base + szA + szB;
  unsigned short* W1t = (unsigned short*)tail;
  unsigned short* W2t = W1t + (size_t)D_IN * D_HID;
  int*   rowptr   = (int*)(W2t + (size_t)D_HID * D_LAT);
  int*   cursor   = rowptr + (Nn + 1);
  int*   es       = cursor + Nn;
  float* wsrt     = (float*)(es + E);
  int*   partials = (int*)(wsrt + E);

  long long n4 = (long long)Nn * D_IN / 4;
  const int nsb = (Nn + 1023) / 1024;   // 49 scan blocks (<= 64 for scan_base)

  // ---- preprocessing: memset -> fused{cast,hist,transposes} -> scan3 -> fill
  hipMemsetAsync(cursor, 0, (size_t)Nn * sizeof(int), stream);
  pre_fused<<<PRE_CAST_B + PRE_HIST_B + PRE_W1_B + PRE_W2_B, 256, 0, stream>>>(
      x, xb, n4, dstp, cursor, E, W1, W1t, W2, W2t);
  scan_partial<<<nsb, 256, 0, stream>>>(cursor, rowptr, partials, Nn);
  scan_base<<<1, 64, 0, stream>>>(partials, nsb);
  scan_apply<<<nsb, 256, 0, stream>>>(cursor, rowptr, partials, Nn);
  fill_csr<<<(E + 255) / 256, 256, 0, stream>>>(dstp, src, ew, cursor, es, wsrt, E);

  // ---- layer 1 ----
  dim3 g1(D_HID / TN, (Nn + TM - 1) / TM);
  gemm_bf16<<<g1, 256, 0, stream>>>(xb, W1t, s1, Nn, D_HID, D_IN);
  gather1_b2b<<<(Nn + 3) / 4, 256, 0, stream>>>(
      s1, es, wsrt, rowptr, b1, hb, Nn);

  // ---- layer 2 ----
  dim3 g2(D_LAT / TN, (Nn + TM - 1) / TM);
  gemm_bf16<<<g2, 256, 0, stream>>>(hb, W2t, s2, Nn, D_LAT, D_HID);
  gather2_b2f<<<(Nn + 7) / 8, 256, 0, stream>>>(
      s2, es, wsrt, rowptr, b2, (float*)d_out, Nn);
}

// Round 5
// 557.446 us; speedup vs baseline: 2.0479x; 1.0276x over previous
//
#include <hip/hip_runtime.h>

typedef __attribute__((ext_vector_type(8))) short short8;
typedef __attribute__((ext_vector_type(4))) float floatx4;

#define GLOBAL_AS __attribute__((address_space(1)))
#define LDS_AS __attribute__((address_space(3)))

__device__ __forceinline__ void gload_lds16(const void* g, void* l) {
  __builtin_amdgcn_global_load_lds((const GLOBAL_AS unsigned int*)g,
                                   (LDS_AS unsigned int*)l, 16, 0, 0);
}

__device__ __forceinline__ unsigned short rnbf(float f) {
  unsigned int v = __builtin_bit_cast(unsigned int, f);
  return (unsigned short)((v + 0x7fff + ((v >> 16) & 1)) >> 16);
}
__device__ __forceinline__ float bflo(unsigned int u) {
  return __builtin_bit_cast(float, u << 16);
}
__device__ __forceinline__ float bfhi(unsigned int u) {
  return __builtin_bit_cast(float, u & 0xffff0000u);
}

// ================= bf16 MFMA GEMM: C[M,N] = A[M,K] @ Bt[N,K]^T ==============
// 128x128 tile, BK=64, 256 thr = 4 waves in 2x2, each wave 64x64 (4x4 MFMA).
// XOR chunk swizzle staging + bijective XCD block swizzle (m204).
// NEW: (a) coalesced epilogue — per-wave LDS restage -> uint4 C stores
//      (b) trailing grid blocks run fill_csr (independent work, hides under
//          gemm compute; branch taken before any barrier)
#define TM 128
#define TN 128
#define BKE 64

__global__ __launch_bounds__(256) void gemm_bf16(
    const unsigned short* __restrict__ A,   // [M,K] bf16
    const unsigned short* __restrict__ Bt,  // [N,K] bf16 (= B^T)
    unsigned short* __restrict__ C,         // [M,N] bf16
    int M, int N, int K, int gx,            // gx = N/TN (col blocks)
    const int* __restrict__ fdst, const int* __restrict__ fsrc,
    const float* __restrict__ fw, int* __restrict__ fcursor,
    int* __restrict__ fes, float* __restrict__ fws, int fE, int ngemm) {
  __shared__ __align__(16) unsigned short As[TM * BKE];
  __shared__ __align__(16) unsigned short Bs[TN * BKE];

  const int bid = blockIdx.x;
  if (bid >= ngemm) {                       // ---- fused fill_csr blocks ----
    const int nfb = gridDim.x - ngemm;
    for (int e = (bid - ngemm) * 256 + threadIdx.x; e < fE; e += nfb * 256) {
      const int pos = atomicAdd(&fcursor[fdst[e]], 1);
      fes[pos] = fsrc[e];
      fws[pos] = fw[e];
    }
    return;
  }

  const int tid  = threadIdx.x;
  const int wave = tid >> 6;
  const int lane = tid & 63;
  const int wm = wave >> 1, wn = wave & 1;
  const int l15 = lane & 15, quad = lane >> 4;

  // bijective XCD swizzle over the gemm blocks
  const int nwg = ngemm;
  const int q = nwg >> 3, r = nwg & 7;
  const int xcd = bid & 7, off = bid >> 3;
  const int lid = ((xcd < r) ? xcd * (q + 1) : r * (q + 1) + (xcd - r) * q) + off;
  const int bm = (lid / gx) * TM;
  const int bn = (lid % gx) * TN;

  floatx4 acc[4][4];
#pragma unroll
  for (int i = 0; i < 4; ++i)
#pragma unroll
    for (int j = 0; j < 4; ++j) acc[i][j] = (floatx4){0.f, 0.f, 0.f, 0.f};

  const unsigned short* aptr[4];
  const unsigned short* bptr[4];
  int ldsoff[4];
#pragma unroll
  for (int j = 0; j < 4; ++j) {
    int ci = (wave * 4 + j) * 64 + lane;   // chunk index in tile
    int rr = ci >> 3;                      // local row 0..127
    int cs = (ci & 7) ^ (rr & 7);          // swizzled source chunk
    int arow = bm + rr; if (arow >= M) arow = M - 1;  // clamp; stores guarded
    aptr[j] = A  + (size_t)arow * K + cs * 8;
    bptr[j] = Bt + (size_t)(bn + rr) * K + cs * 8;    // N % 128 == 0
    ldsoff[j] = (wave * 4 + j) * 64 * 8;   // ushort offset of chunk base
  }

  for (int k0 = 0; k0 < K; k0 += BKE) {
#pragma unroll
    for (int j = 0; j < 4; ++j) {
      gload_lds16(aptr[j] + k0, &As[ldsoff[j]]);
      gload_lds16(bptr[j] + k0, &Bs[ldsoff[j]]);
    }
    __syncthreads();   // drains vmcnt (global_load_lds) + lgkm
#pragma unroll
    for (int s = 0; s < 2; ++s) {
      short8 af[4], bf[4];
#pragma unroll
      for (int mt = 0; mt < 4; ++mt) {
        int mrow = wm * 64 + mt * 16 + l15;
        int sw = (s * 4 + quad) ^ (mrow & 7);
        af[mt] = *(const short8*)&As[(mrow * 8 + sw) * 8];
      }
#pragma unroll
      for (int nt = 0; nt < 4; ++nt) {
        int nrow = wn * 64 + nt * 16 + l15;
        int sw = (s * 4 + quad) ^ (nrow & 7);
        bf[nt] = *(const short8*)&Bs[(nrow * 8 + sw) * 8];
      }
#pragma unroll
      for (int mt = 0; mt < 4; ++mt)
#pragma unroll
        for (int nt = 0; nt < 4; ++nt)
          acc[mt][nt] = __builtin_amdgcn_mfma_f32_16x16x32_bf16(
              af[mt], bf[nt], acc[mt][nt], 0, 0, 0);
    }
    __syncthreads();
  }
  // after this barrier all LDS reads are done -> safe to reuse As

  // ---- coalesced epilogue: per-wave 16x64 bf16 restage in As -------------
  // C/D layout col=lane&15, row=quad*4+i (m89/m91-verified). Values and
  // rounding identical to the old scalar-store path; only write path changes.
  unsigned short* wst = &As[wave * 1024];   // 16 rows x 64 cols ushort (2 KB)
  const int r0 = lane >> 2;                 // readback row 0..15
  const int k0c = lane & 3;                 // readback chunk base
#pragma unroll
  for (int mt = 0; mt < 4; ++mt) {
#pragma unroll
    for (int nt = 0; nt < 4; ++nt) {
#pragma unroll
      for (int i = 0; i < 4; ++i) {
        const int rr = quad * 4 + i;        // local row
        const int cc = nt * 16 + l15;       // local col
        wst[rr * 64 + (((cc >> 3) ^ (rr & 7)) << 3) + (cc & 7)] =
            rnbf(acc[mt][nt][i]);
      }
    }
    const int row_g = bm + wm * 64 + mt * 16 + r0;
#pragma unroll
    for (int kk = 0; kk < 2; ++kk) {
      const int k = k0c + kk * 4;           // chunk 0..7 (8 cols each)
      short8 v = *(const short8*)&wst[r0 * 64 + ((k ^ (r0 & 7)) << 3)];
      if (row_g < M)
        *(short8*)&C[(size_t)row_g * N + bn + wn * 64 + k * 8] = v;
    }
  }
}

// ====== fused independent preprocessing (NO grid.sync — one launch) =========
// blocks [0,1024): cast x f32->bf16 (long pole)
// blocks [1024,1536): hist of dst into cursor (atomic-bound, overlaps cast)
// blocks [1536,2048): W1 transpose-cast;  [2048,2176): W2 transpose-cast
#define PRE_CAST_B 1024
#define PRE_HIST_B 512
#define PRE_W1_B 512
#define PRE_W2_B 128

__global__ __launch_bounds__(256) void pre_fused(
    const float* __restrict__ x, unsigned short* __restrict__ xb, long long n4,
    const int* __restrict__ dst, int* __restrict__ cursor, int E,
    const float* __restrict__ W1, unsigned short* __restrict__ W1t,
    const float* __restrict__ W2, unsigned short* __restrict__ W2t) {
  __shared__ float tile[32][33];
  const int b = blockIdx.x, t = threadIdx.x;
  if (b < PRE_CAST_B) {
    for (long long i = (long long)b * 256 + t; i < n4;
         i += (long long)PRE_CAST_B * 256) {
      float4 v = ((const float4*)x)[i];
      ushort4 o;
      o.x = rnbf(v.x); o.y = rnbf(v.y); o.z = rnbf(v.z); o.w = rnbf(v.w);
      ((ushort4*)xb)[i] = o;
    }
  } else if (b < PRE_CAST_B + PRE_HIST_B) {
    const int bb = b - PRE_CAST_B;
    for (int e = bb * 256 + t; e < E; e += PRE_HIST_B * 256)
      atomicAdd(&cursor[dst[e]], 1);
  } else if (b < PRE_CAST_B + PRE_HIST_B + PRE_W1_B) {
    const int id = b - (PRE_CAST_B + PRE_HIST_B);
    const int bx = (id & 15) * 32, by = (id >> 4) * 32;   // N=512, K=1024
    const int tx = t & 31, ty = t >> 5;
#pragma unroll
    for (int j = 0; j < 4; ++j)
      tile[ty + j * 8][tx] = W1[(size_t)(by + ty + j * 8) * 512 + bx + tx];
    __syncthreads();
#pragma unroll
    for (int j = 0; j < 4; ++j)
      W1t[(size_t)(bx + ty + j * 8) * 1024 + by + tx] = rnbf(tile[tx][ty + j * 8]);
  } else {
    const int id = b - (PRE_CAST_B + PRE_HIST_B + PRE_W1_B);
    const int bx = (id & 7) * 32, by = (id >> 3) * 32;    // N=256, K=512
    const int tx = t & 31, ty = t >> 5;
#pragma unroll
    for (int j = 0; j < 4; ++j)
      tile[ty + j * 8][tx] = W2[(size_t)(by + ty + j * 8) * 256 + bx + tx];
    __syncthreads();
#pragma unroll
    for (int j = 0; j < 4; ++j)
      W2t[(size_t)(bx + ty + j * 8) * 512 + by + tx] = rnbf(tile[tx][ty + j * 8]);
  }
}

// ====== parallel 3-phase scan ==============================================
__global__ __launch_bounds__(256) void scan_partial(
    const int* __restrict__ cursor, int* __restrict__ rowptr,
    int* __restrict__ partials, int n) {
  __shared__ int wsum[4];
  const int t = threadIdx.x, ln = t & 63, wv = t >> 6;
  const int base = blockIdx.x * 1024 + t * 4;
  int4 v = {0, 0, 0, 0};
  if (base + 3 < n) {
    v = *(const int4*)(cursor + base);
  } else {
    if (base + 0 < n) v.x = cursor[base + 0];
    if (base + 1 < n) v.y = cursor[base + 1];
    if (base + 2 < n) v.z = cursor[base + 2];
    if (base + 3 < n) v.w = cursor[base + 3];
  }
  const int s = v.x + v.y + v.z + v.w;
  int inc = s;
#pragma unroll
  for (int o = 1; o < 64; o <<= 1) {
    int y = __shfl_up(inc, o, 64);
    if (ln >= o) inc += y;
  }
  if (ln == 63) wsum[wv] = inc;
  __syncthreads();
  int wpre = 0;
#pragma unroll
  for (int k = 0; k < 4; ++k) wpre += (k < wv) ? wsum[k] : 0;
  const int exc = wpre + inc - s;          // block-local exclusive base
  if (base + 0 < n) rowptr[base + 1] = exc + v.x;
  if (base + 1 < n) rowptr[base + 2] = exc + v.x + v.y;
  if (base + 2 < n) rowptr[base + 3] = exc + v.x + v.y + v.z;
  if (base + 3 < n) rowptr[base + 4] = exc + s;
  if (t == 0) partials[blockIdx.x] = wsum[0] + wsum[1] + wsum[2] + wsum[3];
}

__global__ __launch_bounds__(64) void scan_base(int* partials, int nb) {
  const int t = threadIdx.x;
  const int v = (t < nb) ? partials[t] : 0;
  int inc = v;
#pragma unroll
  for (int o = 1; o < 64; o <<= 1) {
    int y = __shfl_up(inc, o, 64);
    if (t >= o) inc += y;
  }
  if (t < nb) partials[t] = inc - v;       // exclusive
}

__global__ __launch_bounds__(256) void scan_apply(
    int* cursor, int* __restrict__ rowptr, const int* __restrict__ partials,
    int n) {
  const int base = blockIdx.x * 1024 + threadIdx.x * 4;
  const int p = partials[blockIdx.x];
#pragma unroll
  for (int k = 0; k < 4; ++k) {
    const int i = base + k;
    if (i < n) {
      const int cnt = cursor[i];
      const int inc = p + rowptr[i + 1];
      rowptr[i + 1] = inc;
      cursor[i] = inc - cnt;
    }
  }
  if (blockIdx.x == 0 && threadIdx.x == 0) rowptr[0] = 0;
}

// ------- gather layer1: bf16 S [Nn,512] -> bf16 out (bias+relu fused) -------
__global__ __launch_bounds__(256) void gather1_b2b(
    const unsigned short* __restrict__ S, const int* __restrict__ es,
    const float* __restrict__ ws, const int* __restrict__ rowptr,
    const float* __restrict__ bias, unsigned short* __restrict__ out, int Nn) {
  const int tn = threadIdx.x & 63;                 // 64 thr/node, 8 bf16 each
  const int node = blockIdx.x * 4 + (threadIdx.x >> 6);
  if (node >= Nn) return;
  const int f = tn << 3;
  float acc[8] = {};
  const int beg = rowptr[node], end = rowptr[node + 1];
  for (int b = beg; b < end; b += 64) {
    const int m = end - b;
    int   sv_l = 0;
    float w_l  = 0.f;
    if (tn < m) { sv_l = es[b + tn]; w_l = ws[b + tn]; }
    const int cnt = (m < 64) ? m : 64;
    for (int i = 0; i < cnt; ++i) {
      const int   sv = __shfl(sv_l, i, 64);
      const float ww = __shfl(w_l, i, 64);
      const uint4 u = *(const uint4*)(S + (size_t)sv * 512 + f);
      acc[0] = fmaf(bflo(u.x), ww, acc[0]);
      acc[1] = fmaf(bfhi(u.x), ww, acc[1]);
      acc[2] = fmaf(bflo(u.y), ww, acc[2]);
      acc[3] = fmaf(bfhi(u.y), ww, acc[3]);
      acc[4] = fmaf(bflo(u.z), ww, acc[4]);
      acc[5] = fmaf(bfhi(u.z), ww, acc[5]);
      acc[6] = fmaf(bflo(u.w), ww, acc[6]);
      acc[7] = fmaf(bfhi(u.w), ww, acc[7]);
    }
  }
  float r[8];
#pragma unroll
  for (int j = 0; j < 8; ++j) r[j] = fmaxf(acc[j] + bias[f + j], 0.f);
  uint4 o;
  o.x = (unsigned int)rnbf(r[0]) | ((unsigned int)rnbf(r[1]) << 16);
  o.y = (unsigned int)rnbf(r[2]) | ((unsigned int)rnbf(r[3]) << 16);
  o.z = (unsigned int)rnbf(r[4]) | ((unsigned int)rnbf(r[5]) << 16);
  o.w = (unsigned int)rnbf(r[6]) | ((unsigned int)rnbf(r[7]) << 16);
  *(uint4*)(out + (size_t)node * 512 + f) = o;
}

// ------- gather layer2: bf16 S [Nn,256] -> f32 out (bias+relu fused) --------
__global__ __launch_bounds__(256) void gather2_b2f(
    const unsigned short* __restrict__ S, const int* __restrict__ es,
    const float* __restrict__ ws, const int* __restrict__ rowptr,
    const float* __restrict__ bias, float* __restrict__ out, int Nn) {
  const int tn = threadIdx.x & 31;                 // 32 thr/node, 8 bf16 each
  const int node = blockIdx.x * 8 + (threadIdx.x >> 5);
  if (node >= Nn) return;
  const int f = tn << 3;
  float acc[8] = {};
  const int beg = rowptr[node], end = rowptr[node + 1];
  for (int b = beg; b < end; b += 32) {
    const int m = end - b;
    int   sv_l = 0;
    float w_l  = 0.f;
    if (tn < m) { sv_l = es[b + tn]; w_l = ws[b + tn]; }
    const int cnt = (m < 32) ? m : 32;
    for (int i = 0; i < cnt; ++i) {
      const int   sv = __shfl(sv_l, i, 32);
      const float ww = __shfl(w_l, i, 32);
      const uint4 u = *(const uint4*)(S + (size_t)sv * 256 + f);
      acc[0] = fmaf(bflo(u.x), ww, acc[0]);
      acc[1] = fmaf(bfhi(u.x), ww, acc[1]);
      acc[2] = fmaf(bflo(u.y), ww, acc[2]);
      acc[3] = fmaf(bfhi(u.y), ww, acc[3]);
      acc[4] = fmaf(bflo(u.z), ww, acc[4]);
      acc[5] = fmaf(bfhi(u.z), ww, acc[5]);
      acc[6] = fmaf(bflo(u.w), ww, acc[6]);
      acc[7] = fmaf(bfhi(u.w), ww, acc[7]);
    }
  }
  float4 o1, o2;
  o1.x = fmaxf(acc[0] + bias[f + 0], 0.f);
  o1.y = fmaxf(acc[1] + bias[f + 1], 0.f);
  o1.z = fmaxf(acc[2] + bias[f + 2], 0.f);
  o1.w = fmaxf(acc[3] + bias[f + 3], 0.f);
  o2.x = fmaxf(acc[4] + bias[f + 4], 0.f);
  o2.y = fmaxf(acc[5] + bias[f + 5], 0.f);
  o2.z = fmaxf(acc[6] + bias[f + 6], 0.f);
  o2.w = fmaxf(acc[7] + bias[f + 7], 0.f);
  *(float4*)(out + (size_t)node * 256 + f) = o1;
  *(float4*)(out + (size_t)node * 256 + f + 4) = o2;
}

// ============================================================================
extern "C" void kernel_launch(void* const* d_in, const int* in_sizes, int n_in,
                              void* d_out, int out_size, void* d_ws, size_t ws_size,
                              hipStream_t stream) {
  const float* x  = (const float*)d_in[0];
  const int*   ei = (const int*)d_in[1];
  const float* ew = (const float*)d_in[2];
  const float* W1 = (const float*)d_in[3];
  const float* b1 = (const float*)d_in[4];
  const float* W2 = (const float*)d_in[5];
  const float* b2 = (const float*)d_in[6];

  const int D_IN = 1024, D_HID = 512, D_LAT = 256;
  const int Nn = in_sizes[0] / D_IN;   // 50000
  const int E  = in_sizes[2];          // 400000
  const int* src  = ei;
  const int* dstp = ei + E;

  // ws layout (region A aliases xb->hb, region B aliases s1->s2):
  //  A: [0, Nn*1024*2)            xb bf16; later hb bf16
  //  B: [A, A + Nn*512*2)         s1 bf16; later s2 bf16
  //  C: W1t, W2t, rowptr, cursor, es, ws, partials         (~5 MB)
  char* base = (char*)d_ws;
  const size_t szA = (size_t)Nn * D_IN * 2;
  const size_t szB = (size_t)Nn * D_HID * 2;
  unsigned short* xb  = (unsigned short*)base;
  unsigned short* hb  = (unsigned short*)base;             // alias, xb dead
  unsigned short* s1  = (unsigned short*)(base + szA);
  unsigned short* s2  = (unsigned short*)(base + szA);     // alias, s1 dead
  char* tail = base + szA + szB;
  unsigned short* W1t = (unsigned short*)tail;
  unsigned short* W2t = W1t + (size_t)D_IN * D_HID;
  int*   rowptr   = (int*)(W2t + (size_t)D_HID * D_LAT);
  int*   cursor   = rowptr + (Nn + 1);
  int*   es       = cursor + Nn;
  float* wsrt     = (float*)(es + E);
  int*   partials = (int*)(wsrt + E);

  long long n4 = (long long)Nn * D_IN / 4;
  const int nsb = (Nn + 1023) / 1024;   // 49 scan blocks (<= 64 for scan_base)

  // ---- preprocessing: memset -> fused{cast,hist,transposes} -> scan3 -------
  hipMemsetAsync(cursor, 0, (size_t)Nn * sizeof(int), stream);
  pre_fused<<<PRE_CAST_B + PRE_HIST_B + PRE_W1_B + PRE_W2_B, 256, 0, stream>>>(
      x, xb, n4, dstp, cursor, E, W1, W1t, W2, W2t);
  scan_partial<<<nsb, 256, 0, stream>>>(cursor, rowptr, partials, Nn);
  scan_base<<<1, 64, 0, stream>>>(partials, nsb);
  scan_apply<<<nsb, 256, 0, stream>>>(cursor, rowptr, partials, Nn);

  // ---- layer 1: gemm1 with fused fill_csr trailing blocks ----
  const int gx1 = D_HID / TN;                 // 4
  const int gy1 = (Nn + TM - 1) / TM;         // 391
  const int ng1 = gx1 * gy1;
  const int nfill = 512;
  gemm_bf16<<<ng1 + nfill, 256, 0, stream>>>(
      xb, W1t, s1, Nn, D_HID, D_IN, gx1,
      dstp, src, ew, cursor, es, wsrt, E, ng1);
  gather1_b2b<<<(Nn + 3) / 4, 256, 0, stream>>>(
      s1, es, wsrt, rowptr, b1, hb, Nn);

  // ---- layer 2 ----
  const int gx2 = D_LAT / TN;                 // 2
  const int ng2 = gx2 * gy1;
  gemm_bf16<<<ng2, 256, 0, stream>>>(
      hb, W2t, s2, Nn, D_LAT, D_HID, gx2,
      nullptr, nullptr, nullptr, nullptr, nullptr, nullptr, 0, ng2);
  gather2_b2f<<<(Nn + 7) / 8, 256, 0, stream>>>(
      s2, es, wsrt, rowptr, b2, (float*)d_out, Nn);
}

// Round 6
// 535.802 us; speedup vs baseline: 2.1307x; 1.0404x over previous
//
#include <hip/hip_runtime.h>

typedef __attribute__((ext_vector_type(8))) short short8;
typedef __attribute__((ext_vector_type(4))) float floatx4;

#define GLOBAL_AS __attribute__((address_space(1)))
#define LDS_AS __attribute__((address_space(3)))

__device__ __forceinline__ void gload_lds16(const void* g, void* l) {
  __builtin_amdgcn_global_load_lds((const GLOBAL_AS unsigned int*)g,
                                   (LDS_AS unsigned int*)l, 16, 0, 0);
}

__device__ __forceinline__ unsigned short rnbf(float f) {
  unsigned int v = __builtin_bit_cast(unsigned int, f);
  return (unsigned short)((v + 0x7fff + ((v >> 16) & 1)) >> 16);
}
__device__ __forceinline__ float bflo(unsigned int u) {
  return __builtin_bit_cast(float, u << 16);
}
__device__ __forceinline__ float bfhi(unsigned int u) {
  return __builtin_bit_cast(float, u & 0xffff0000u);
}

// ================= bf16 MFMA GEMM: C[M,N] = A[M,K] @ Bt[N,K]^T ==============
// 128x128 tile, BK=64, 256 thr = 4 waves in 2x2, each wave 64x64 (4x4 MFMA).
// XOR chunk swizzle staging + bijective XCD block swizzle + coalesced
// LDS-restage epilogue + optional fused fill_csr trailing blocks.
// A_F32=1: A is f32; cast to bf16 in-register during staging (same rnbf
// rounding, same swizzled LDS layout -> bit-identical to pre-cast path).
#define TM 128
#define TN 128
#define BKE 64

template <int A_F32>
__global__ __launch_bounds__(256) void gemm_bf16_t(
    const void* __restrict__ Ap,            // [M,K] bf16 or f32
    const unsigned short* __restrict__ Bt,  // [N,K] bf16 (= B^T)
    unsigned short* __restrict__ C,         // [M,N] bf16
    int M, int N, int K, int gx,            // gx = N/TN (col blocks)
    const int* __restrict__ fdst, const int* __restrict__ fsrc,
    const float* __restrict__ fw, int* __restrict__ fcursor,
    int* __restrict__ fes, float* __restrict__ fws, int fE, int ngemm) {
  __shared__ __align__(16) unsigned short As[TM * BKE];
  __shared__ __align__(16) unsigned short Bs[TN * BKE];

  const int bid = blockIdx.x;
  if (bid >= ngemm) {                       // ---- fused fill_csr blocks ----
    const int nfb = gridDim.x - ngemm;
    for (int e = (bid - ngemm) * 256 + threadIdx.x; e < fE; e += nfb * 256) {
      const int pos = atomicAdd(&fcursor[fdst[e]], 1);
      fes[pos] = fsrc[e];
      fws[pos] = fw[e];
    }
    return;
  }

  const int tid  = threadIdx.x;
  const int wave = tid >> 6;
  const int lane = tid & 63;
  const int wm = wave >> 1, wn = wave & 1;
  const int l15 = lane & 15, quad = lane >> 4;

  // bijective XCD swizzle over the gemm blocks
  const int nwg = ngemm;
  const int q = nwg >> 3, r = nwg & 7;
  const int xcd = bid & 7, off = bid >> 3;
  const int lid = ((xcd < r) ? xcd * (q + 1) : r * (q + 1) + (xcd - r) * q) + off;
  const int bm = (lid / gx) * TM;
  const int bn = (lid % gx) * TN;

  floatx4 acc[4][4];
#pragma unroll
  for (int i = 0; i < 4; ++i)
#pragma unroll
    for (int j = 0; j < 4; ++j) acc[i][j] = (floatx4){0.f, 0.f, 0.f, 0.f};

  const unsigned short* aptrb[4];
  const float* aptrf[4];
  const unsigned short* bptr[4];
  int ldsoff[4];
#pragma unroll
  for (int j = 0; j < 4; ++j) {
    int ci = (wave * 4 + j) * 64 + lane;   // chunk index in tile
    int rr = ci >> 3;                      // local row 0..127
    int cs = (ci & 7) ^ (rr & 7);          // swizzled source chunk
    int arow = bm + rr; if (arow >= M) arow = M - 1;  // clamp; stores guarded
    if constexpr (A_F32)
      aptrf[j] = (const float*)Ap + (size_t)arow * K + cs * 8;
    else
      aptrb[j] = (const unsigned short*)Ap + (size_t)arow * K + cs * 8;
    bptr[j] = Bt + (size_t)(bn + rr) * K + cs * 8;    // N % 128 == 0
    ldsoff[j] = (wave * 4 + j) * 64 * 8;   // ushort offset of chunk base
  }

  for (int k0 = 0; k0 < K; k0 += BKE) {
    if constexpr (A_F32) {
      float4 av[4][2];
#pragma unroll
      for (int j = 0; j < 4; ++j) {
        const float4* p = (const float4*)(aptrf[j] + k0);
        av[j][0] = p[0];
        av[j][1] = p[1];
      }
#pragma unroll
      for (int j = 0; j < 4; ++j)
        gload_lds16(bptr[j] + k0, &Bs[ldsoff[j]]);
#pragma unroll
      for (int j = 0; j < 4; ++j) {
        short8 t;
        t[0] = (short)rnbf(av[j][0].x); t[1] = (short)rnbf(av[j][0].y);
        t[2] = (short)rnbf(av[j][0].z); t[3] = (short)rnbf(av[j][0].w);
        t[4] = (short)rnbf(av[j][1].x); t[5] = (short)rnbf(av[j][1].y);
        t[6] = (short)rnbf(av[j][1].z); t[7] = (short)rnbf(av[j][1].w);
        *(short8*)&As[ldsoff[j] + lane * 8] = t;   // same swizzled layout
      }
    } else {
#pragma unroll
      for (int j = 0; j < 4; ++j) {
        gload_lds16(aptrb[j] + k0, &As[ldsoff[j]]);
        gload_lds16(bptr[j] + k0, &Bs[ldsoff[j]]);
      }
    }
    __syncthreads();   // drains vmcnt (gload_lds / loads) + lgkm (ds_write)
#pragma unroll
    for (int s = 0; s < 2; ++s) {
      short8 af[4], bf[4];
#pragma unroll
      for (int mt = 0; mt < 4; ++mt) {
        int mrow = wm * 64 + mt * 16 + l15;
        int sw = (s * 4 + quad) ^ (mrow & 7);
        af[mt] = *(const short8*)&As[(mrow * 8 + sw) * 8];
      }
#pragma unroll
      for (int nt = 0; nt < 4; ++nt) {
        int nrow = wn * 64 + nt * 16 + l15;
        int sw = (s * 4 + quad) ^ (nrow & 7);
        bf[nt] = *(const short8*)&Bs[(nrow * 8 + sw) * 8];
      }
#pragma unroll
      for (int mt = 0; mt < 4; ++mt)
#pragma unroll
        for (int nt = 0; nt < 4; ++nt)
          acc[mt][nt] = __builtin_amdgcn_mfma_f32_16x16x32_bf16(
              af[mt], bf[nt], acc[mt][nt], 0, 0, 0);
    }
    __syncthreads();
  }
  // after this barrier all LDS reads are done -> safe to reuse As

  // ---- coalesced epilogue: per-wave 16x64 bf16 restage in As -------------
  unsigned short* wst = &As[wave * 1024];   // 16 rows x 64 cols ushort (2 KB)
  const int r0 = lane >> 2;                 // readback row 0..15
  const int k0c = lane & 3;                 // readback chunk base
#pragma unroll
  for (int mt = 0; mt < 4; ++mt) {
#pragma unroll
    for (int nt = 0; nt < 4; ++nt) {
#pragma unroll
      for (int i = 0; i < 4; ++i) {
        const int rr = quad * 4 + i;        // local row
        const int cc = nt * 16 + l15;       // local col
        wst[rr * 64 + (((cc >> 3) ^ (rr & 7)) << 3) + (cc & 7)] =
            rnbf(acc[mt][nt][i]);
      }
    }
    const int row_g = bm + wm * 64 + mt * 16 + r0;
#pragma unroll
    for (int kk = 0; kk < 2; ++kk) {
      const int k = k0c + kk * 4;           // chunk 0..7 (8 cols each)
      short8 v = *(const short8*)&wst[r0 * 64 + ((k ^ (r0 & 7)) << 3)];
      if (row_g < M)
        *(short8*)&C[(size_t)row_g * N + bn + wn * 64 + k * 8] = v;
    }
  }
}

// ====== fused independent preprocessing (cast now fused into gemm1) =========
// blocks [0,512): hist of dst into cursor (atomic-bound)
// blocks [512,1024): W1 transpose-cast;  [1024,1152): W2 transpose-cast
#define PRE_HIST_B 512
#define PRE_W1_B 512
#define PRE_W2_B 128

__global__ __launch_bounds__(256) void pre_fused(
    const int* __restrict__ dst, int* __restrict__ cursor, int E,
    const float* __restrict__ W1, unsigned short* __restrict__ W1t,
    const float* __restrict__ W2, unsigned short* __restrict__ W2t) {
  __shared__ float tile[32][33];
  const int b = blockIdx.x, t = threadIdx.x;
  if (b < PRE_HIST_B) {
    for (int e = b * 256 + t; e < E; e += PRE_HIST_B * 256)
      atomicAdd(&cursor[dst[e]], 1);
  } else if (b < PRE_HIST_B + PRE_W1_B) {
    const int id = b - PRE_HIST_B;
    const int bx = (id & 15) * 32, by = (id >> 4) * 32;   // N=512, K=1024
    const int tx = t & 31, ty = t >> 5;
#pragma unroll
    for (int j = 0; j < 4; ++j)
      tile[ty + j * 8][tx] = W1[(size_t)(by + ty + j * 8) * 512 + bx + tx];
    __syncthreads();
#pragma unroll
    for (int j = 0; j < 4; ++j)
      W1t[(size_t)(bx + ty + j * 8) * 1024 + by + tx] = rnbf(tile[tx][ty + j * 8]);
  } else {
    const int id = b - (PRE_HIST_B + PRE_W1_B);
    const int bx = (id & 7) * 32, by = (id >> 3) * 32;    // N=256, K=512
    const int tx = t & 31, ty = t >> 5;
#pragma unroll
    for (int j = 0; j < 4; ++j)
      tile[ty + j * 8][tx] = W2[(size_t)(by + ty + j * 8) * 256 + bx + tx];
    __syncthreads();
#pragma unroll
    for (int j = 0; j < 4; ++j)
      W2t[(size_t)(bx + ty + j * 8) * 512 + by + tx] = rnbf(tile[tx][ty + j * 8]);
  }
}

// ====== parallel 3-phase scan ==============================================
__global__ __launch_bounds__(256) void scan_partial(
    const int* __restrict__ cursor, int* __restrict__ rowptr,
    int* __restrict__ partials, int n) {
  __shared__ int wsum[4];
  const int t = threadIdx.x, ln = t & 63, wv = t >> 6;
  const int base = blockIdx.x * 1024 + t * 4;
  int4 v = {0, 0, 0, 0};
  if (base + 3 < n) {
    v = *(const int4*)(cursor + base);
  } else {
    if (base + 0 < n) v.x = cursor[base + 0];
    if (base + 1 < n) v.y = cursor[base + 1];
    if (base + 2 < n) v.z = cursor[base + 2];
    if (base + 3 < n) v.w = cursor[base + 3];
  }
  const int s = v.x + v.y + v.z + v.w;
  int inc = s;
#pragma unroll
  for (int o = 1; o < 64; o <<= 1) {
    int y = __shfl_up(inc, o, 64);
    if (ln >= o) inc += y;
  }
  if (ln == 63) wsum[wv] = inc;
  __syncthreads();
  int wpre = 0;
#pragma unroll
  for (int k = 0; k < 4; ++k) wpre += (k < wv) ? wsum[k] : 0;
  const int exc = wpre + inc - s;          // block-local exclusive base
  if (base + 0 < n) rowptr[base + 1] = exc + v.x;
  if (base + 1 < n) rowptr[base + 2] = exc + v.x + v.y;
  if (base + 2 < n) rowptr[base + 3] = exc + v.x + v.y + v.z;
  if (base + 3 < n) rowptr[base + 4] = exc + s;
  if (t == 0) partials[blockIdx.x] = wsum[0] + wsum[1] + wsum[2] + wsum[3];
}

__global__ __launch_bounds__(64) void scan_base(int* partials, int nb) {
  const int t = threadIdx.x;
  const int v = (t < nb) ? partials[t] : 0;
  int inc = v;
#pragma unroll
  for (int o = 1; o < 64; o <<= 1) {
    int y = __shfl_up(inc, o, 64);
    if (t >= o) inc += y;
  }
  if (t < nb) partials[t] = inc - v;       // exclusive
}

__global__ __launch_bounds__(256) void scan_apply(
    int* cursor, int* __restrict__ rowptr, const int* __restrict__ partials,
    int n) {
  const int base = blockIdx.x * 1024 + threadIdx.x * 4;
  const int p = partials[blockIdx.x];
#pragma unroll
  for (int k = 0; k < 4; ++k) {
    const int i = base + k;
    if (i < n) {
      const int cnt = cursor[i];
      const int inc = p + rowptr[i + 1];
      rowptr[i + 1] = inc;
      cursor[i] = inc - cnt;
    }
  }
  if (blockIdx.x == 0 && threadIdx.x == 0) rowptr[0] = 0;
}

// ------- gather layer1: bf16 S [Nn,512] -> bf16 out (bias+relu fused) -------
__global__ __launch_bounds__(256) void gather1_b2b(
    const unsigned short* __restrict__ S, const int* __restrict__ es,
    const float* __restrict__ ws, const int* __restrict__ rowptr,
    const float* __restrict__ bias, unsigned short* __restrict__ out, int Nn) {
  const int tn = threadIdx.x & 63;                 // 64 thr/node, 8 bf16 each
  const int node = blockIdx.x * 4 + (threadIdx.x >> 6);
  if (node >= Nn) return;
  const int f = tn << 3;
  float acc[8] = {};
  const int beg = rowptr[node], end = rowptr[node + 1];
  for (int b = beg; b < end; b += 64) {
    const int m = end - b;
    int   sv_l = 0;
    float w_l  = 0.f;
    if (tn < m) { sv_l = es[b + tn]; w_l = ws[b + tn]; }
    const int cnt = (m < 64) ? m : 64;
#pragma unroll 2
    for (int i = 0; i < cnt; ++i) {
      const int   sv = __shfl(sv_l, i, 64);
      const float ww = __shfl(w_l, i, 64);
      const uint4 u = *(const uint4*)(S + (size_t)sv * 512 + f);
      acc[0] = fmaf(bflo(u.x), ww, acc[0]);
      acc[1] = fmaf(bfhi(u.x), ww, acc[1]);
      acc[2] = fmaf(bflo(u.y), ww, acc[2]);
      acc[3] = fmaf(bfhi(u.y), ww, acc[3]);
      acc[4] = fmaf(bflo(u.z), ww, acc[4]);
      acc[5] = fmaf(bfhi(u.z), ww, acc[5]);
      acc[6] = fmaf(bflo(u.w), ww, acc[6]);
      acc[7] = fmaf(bfhi(u.w), ww, acc[7]);
    }
  }
  float r[8];
#pragma unroll
  for (int j = 0; j < 8; ++j) r[j] = fmaxf(acc[j] + bias[f + j], 0.f);
  uint4 o;
  o.x = (unsigned int)rnbf(r[0]) | ((unsigned int)rnbf(r[1]) << 16);
  o.y = (unsigned int)rnbf(r[2]) | ((unsigned int)rnbf(r[3]) << 16);
  o.z = (unsigned int)rnbf(r[4]) | ((unsigned int)rnbf(r[5]) << 16);
  o.w = (unsigned int)rnbf(r[6]) | ((unsigned int)rnbf(r[7]) << 16);
  *(uint4*)(out + (size_t)node * 512 + f) = o;
}

// ------- gather layer2: bf16 S [Nn,256] -> f32 out (bias+relu fused) --------
__global__ __launch_bounds__(256) void gather2_b2f(
    const unsigned short* __restrict__ S, const int* __restrict__ es,
    const float* __restrict__ ws, const int* __restrict__ rowptr,
    const float* __restrict__ bias, float* __restrict__ out, int Nn) {
  const int tn = threadIdx.x & 31;                 // 32 thr/node, 8 bf16 each
  const int node = blockIdx.x * 8 + (threadIdx.x >> 5);
  if (node >= Nn) return;
  const int f = tn << 3;
  float acc[8] = {};
  const int beg = rowptr[node], end = rowptr[node + 1];
  for (int b = beg; b < end; b += 32) {
    const int m = end - b;
    int   sv_l = 0;
    float w_l  = 0.f;
    if (tn < m) { sv_l = es[b + tn]; w_l = ws[b + tn]; }
    const int cnt = (m < 32) ? m : 32;
#pragma unroll 2
    for (int i = 0; i < cnt; ++i) {
      const int   sv = __shfl(sv_l, i, 32);
      const float ww = __shfl(w_l, i, 32);
      const uint4 u = *(const uint4*)(S + (size_t)sv * 256 + f);
      acc[0] = fmaf(bflo(u.x), ww, acc[0]);
      acc[1] = fmaf(bfhi(u.x), ww, acc[1]);
      acc[2] = fmaf(bflo(u.y), ww, acc[2]);
      acc[3] = fmaf(bfhi(u.y), ww, acc[3]);
      acc[4] = fmaf(bflo(u.z), ww, acc[4]);
      acc[5] = fmaf(bfhi(u.z), ww, acc[5]);
      acc[6] = fmaf(bflo(u.w), ww, acc[6]);
      acc[7] = fmaf(bfhi(u.w), ww, acc[7]);
    }
  }
  float4 o1, o2;
  o1.x = fmaxf(acc[0] + bias[f + 0], 0.f);
  o1.y = fmaxf(acc[1] + bias[f + 1], 0.f);
  o1.z = fmaxf(acc[2] + bias[f + 2], 0.f);
  o1.w = fmaxf(acc[3] + bias[f + 3], 0.f);
  o2.x = fmaxf(acc[4] + bias[f + 4], 0.f);
  o2.y = fmaxf(acc[5] + bias[f + 5], 0.f);
  o2.z = fmaxf(acc[6] + bias[f + 6], 0.f);
  o2.w = fmaxf(acc[7] + bias[f + 7], 0.f);
  *(float4*)(out + (size_t)node * 256 + f) = o1;
  *(float4*)(out + (size_t)node * 256 + f + 4) = o2;
}

// ============================================================================
extern "C" void kernel_launch(void* const* d_in, const int* in_sizes, int n_in,
                              void* d_out, int out_size, void* d_ws, size_t ws_size,
                              hipStream_t stream) {
  const float* x  = (const float*)d_in[0];
  const int*   ei = (const int*)d_in[1];
  const float* ew = (const float*)d_in[2];
  const float* W1 = (const float*)d_in[3];
  const float* b1 = (const float*)d_in[4];
  const float* W2 = (const float*)d_in[5];
  const float* b2 = (const float*)d_in[6];

  const int D_IN = 1024, D_HID = 512, D_LAT = 256;
  const int Nn = in_sizes[0] / D_IN;   // 50000
  const int E  = in_sizes[2];          // 400000
  const int* src  = ei;
  const int* dstp = ei + E;

  // ws layout (region A holds hb; region B aliases s1->s2):
  //  A: [0, Nn*1024*2)            hb bf16 (x is read f32 directly by gemm1)
  //  B: [A, A + Nn*512*2)         s1 bf16; later s2 bf16
  //  C: W1t, W2t, rowptr, cursor, es, ws, partials         (~5 MB)
  char* base = (char*)d_ws;
  const size_t szA = (size_t)Nn * D_IN * 2;
  const size_t szB = (size_t)Nn * D_HID * 2;
  unsigned short* hb  = (unsigned short*)base;
  unsigned short* s1  = (unsigned short*)(base + szA);
  unsigned short* s2  = (unsigned short*)(base + szA);     // alias, s1 dead
  char* tail = base + szA + szB;
  unsigned short* W1t = (unsigned short*)tail;
  unsigned short* W2t = W1t + (size_t)D_IN * D_HID;
  int*   rowptr   = (int*)(W2t + (size_t)D_HID * D_LAT);
  int*   cursor   = rowptr + (Nn + 1);
  int*   es       = cursor + Nn;
  float* wsrt     = (float*)(es + E);
  int*   partials = (int*)(wsrt + E);

  const int nsb = (Nn + 1023) / 1024;   // 49 scan blocks (<= 64 for scan_base)

  // ---- preprocessing: memset -> fused{hist,transposes} -> scan3 ------------
  hipMemsetAsync(cursor, 0, (size_t)Nn * sizeof(int), stream);
  pre_fused<<<PRE_HIST_B + PRE_W1_B + PRE_W2_B, 256, 0, stream>>>(
      dstp, cursor, E, W1, W1t, W2, W2t);
  scan_partial<<<nsb, 256, 0, stream>>>(cursor, rowptr, partials, Nn);
  scan_base<<<1, 64, 0, stream>>>(partials, nsb);
  scan_apply<<<nsb, 256, 0, stream>>>(cursor, rowptr, partials, Nn);

  // ---- layer 1: gemm1 (A = f32 x, cast fused) + fill_csr trailing blocks ---
  const int gx1 = D_HID / TN;                 // 4
  const int gy1 = (Nn + TM - 1) / TM;         // 391
  const int ng1 = gx1 * gy1;
  const int nfill = 512;
  gemm_bf16_t<1><<<ng1 + nfill, 256, 0, stream>>>(
      (const void*)x, W1t, s1, Nn, D_HID, D_IN, gx1,
      dstp, src, ew, cursor, es, wsrt, E, ng1);
  gather1_b2b<<<(Nn + 3) / 4, 256, 0, stream>>>(
      s1, es, wsrt, rowptr, b1, hb, Nn);

  // ---- layer 2 ----
  const int gx2 = D_LAT / TN;                 // 2
  const int ng2 = gx2 * gy1;
  gemm_bf16_t<0><<<ng2, 256, 0, stream>>>(
      (const void*)hb, W2t, s2, Nn, D_LAT, D_HID, gx2,
      nullptr, nullptr, nullptr, nullptr, nullptr, nullptr, 0, ng2);
  gather2_b2f<<<(Nn + 7) / 8, 256, 0, stream>>>(
      s2, es, wsrt, rowptr, b2, (float*)d_out, Nn);
}

// Round 7
// 508.895 us; speedup vs baseline: 2.2433x; 1.0529x over previous
//
#include <hip/hip_runtime.h>

typedef __attribute__((ext_vector_type(8))) short short8;
typedef __attribute__((ext_vector_type(4))) float floatx4;

#define GLOBAL_AS __attribute__((address_space(1)))
#define LDS_AS __attribute__((address_space(3)))

__device__ __forceinline__ void gload_lds16(const void* g, void* l) {
  __builtin_amdgcn_global_load_lds((const GLOBAL_AS unsigned int*)g,
                                   (LDS_AS unsigned int*)l, 16, 0, 0);
}

__device__ __forceinline__ unsigned short rnbf(float f) {
  unsigned int v = __builtin_bit_cast(unsigned int, f);
  return (unsigned short)((v + 0x7fff + ((v >> 16) & 1)) >> 16);
}
__device__ __forceinline__ float bflo(unsigned int u) {
  return __builtin_bit_cast(float, u << 16);
}
__device__ __forceinline__ float bfhi(unsigned int u) {
  return __builtin_bit_cast(float, u & 0xffff0000u);
}

// ================= bf16 MFMA GEMM: C[M,N] = A[M,K] @ Bt[N,K]^T ==============
// 128x128 tile, BK=64, 256 thr = 4 waves in 2x2, each wave 64x64 (4x4 MFMA).
// XOR chunk swizzle staging + bijective XCD block swizzle + coalesced
// LDS-restage epilogue + optional fused fill_csr trailing blocks.
// A_F32=1: A is f32, cast fused into staging with T14 issue-early split:
//   regs hold tile k (loaded during iter k-1's MFMA); per iter:
//   stage B (gload_lds) -> cvt+ds_write A regs -> sync -> ISSUE tile k+1
//   A loads (latency hides under MFMA) -> MFMA -> sync.
#define TM 128
#define TN 128
#define BKE 64

template <int A_F32>
__global__ __launch_bounds__(256) void gemm_bf16_t(
    const void* __restrict__ Ap,            // [M,K] bf16 or f32
    const unsigned short* __restrict__ Bt,  // [N,K] bf16 (= B^T)
    unsigned short* __restrict__ C,         // [M,N] bf16
    int M, int N, int K, int gx,            // gx = N/TN (col blocks)
    const int* __restrict__ fdst, const int* __restrict__ fsrc,
    const float* __restrict__ fw, int* __restrict__ fcursor,
    int* __restrict__ fes, float* __restrict__ fws, int fE, int ngemm) {
  __shared__ __align__(16) unsigned short As[TM * BKE];
  __shared__ __align__(16) unsigned short Bs[TN * BKE];

  const int bid = blockIdx.x;
  if (bid >= ngemm) {                       // ---- fused fill_csr blocks ----
    const int nfb = gridDim.x - ngemm;
    for (int e = (bid - ngemm) * 256 + threadIdx.x; e < fE; e += nfb * 256) {
      const int pos = atomicAdd(&fcursor[fdst[e]], 1);
      fes[pos] = fsrc[e];
      fws[pos] = fw[e];
    }
    return;
  }

  const int tid  = threadIdx.x;
  const int wave = tid >> 6;
  const int lane = tid & 63;
  const int wm = wave >> 1, wn = wave & 1;
  const int l15 = lane & 15, quad = lane >> 4;

  // bijective XCD swizzle over the gemm blocks
  const int nwg = ngemm;
  const int q = nwg >> 3, r = nwg & 7;
  const int xcd = bid & 7, off = bid >> 3;
  const int lid = ((xcd < r) ? xcd * (q + 1) : r * (q + 1) + (xcd - r) * q) + off;
  const int bm = (lid / gx) * TM;
  const int bn = (lid % gx) * TN;

  floatx4 acc[4][4];
#pragma unroll
  for (int i = 0; i < 4; ++i)
#pragma unroll
    for (int j = 0; j < 4; ++j) acc[i][j] = (floatx4){0.f, 0.f, 0.f, 0.f};

  const unsigned short* aptrb[4];
  const float* aptrf[4];
  const unsigned short* bptr[4];
  int ldsoff[4];
#pragma unroll
  for (int j = 0; j < 4; ++j) {
    int ci = (wave * 4 + j) * 64 + lane;   // chunk index in tile
    int rr = ci >> 3;                      // local row 0..127
    int cs = (ci & 7) ^ (rr & 7);          // swizzled source chunk
    int arow = bm + rr; if (arow >= M) arow = M - 1;  // clamp; stores guarded
    if constexpr (A_F32)
      aptrf[j] = (const float*)Ap + (size_t)arow * K + cs * 8;
    else
      aptrb[j] = (const unsigned short*)Ap + (size_t)arow * K + cs * 8;
    bptr[j] = Bt + (size_t)(bn + rr) * K + cs * 8;    // N % 128 == 0
    ldsoff[j] = (wave * 4 + j) * 64 * 8;   // ushort offset of chunk base
  }

  float4 av[4][2];
  if constexpr (A_F32) {
    // prologue: load A tile 0 into registers
#pragma unroll
    for (int j = 0; j < 4; ++j) {
      const float4* p = (const float4*)(aptrf[j]);
      av[j][0] = p[0];
      av[j][1] = p[1];
    }
  }

  for (int k0 = 0; k0 < K; k0 += BKE) {
    if constexpr (A_F32) {
      // B first: fire-and-forget while we convert A
#pragma unroll
      for (int j = 0; j < 4; ++j)
        gload_lds16(bptr[j] + k0, &Bs[ldsoff[j]]);
      // convert + write the ALREADY-LOADED A regs (tile k0)
#pragma unroll
      for (int j = 0; j < 4; ++j) {
        short8 t;
        t[0] = (short)rnbf(av[j][0].x); t[1] = (short)rnbf(av[j][0].y);
        t[2] = (short)rnbf(av[j][0].z); t[3] = (short)rnbf(av[j][0].w);
        t[4] = (short)rnbf(av[j][1].x); t[5] = (short)rnbf(av[j][1].y);
        t[6] = (short)rnbf(av[j][1].z); t[7] = (short)rnbf(av[j][1].w);
        *(short8*)&As[ldsoff[j] + lane * 8] = t;   // same swizzled layout
      }
    } else {
#pragma unroll
      for (int j = 0; j < 4; ++j) {
        gload_lds16(aptrb[j] + k0, &As[ldsoff[j]]);
        gload_lds16(bptr[j] + k0, &Bs[ldsoff[j]]);
      }
    }
    __syncthreads();   // drains vmcnt (gload_lds / loads) + lgkm (ds_write)

    if constexpr (A_F32) {
      // T14 issue-early: next tile's A loads fly during the MFMA cluster
      if (k0 + BKE < K) {
#pragma unroll
        for (int j = 0; j < 4; ++j) {
          const float4* p = (const float4*)(aptrf[j] + k0 + BKE);
          av[j][0] = p[0];
          av[j][1] = p[1];
        }
      }
    }

#pragma unroll
    for (int s = 0; s < 2; ++s) {
      short8 af[4], bf[4];
#pragma unroll
      for (int mt = 0; mt < 4; ++mt) {
        int mrow = wm * 64 + mt * 16 + l15;
        int sw = (s * 4 + quad) ^ (mrow & 7);
        af[mt] = *(const short8*)&As[(mrow * 8 + sw) * 8];
      }
#pragma unroll
      for (int nt = 0; nt < 4; ++nt) {
        int nrow = wn * 64 + nt * 16 + l15;
        int sw = (s * 4 + quad) ^ (nrow & 7);
        bf[nt] = *(const short8*)&Bs[(nrow * 8 + sw) * 8];
      }
#pragma unroll
      for (int mt = 0; mt < 4; ++mt)
#pragma unroll
        for (int nt = 0; nt < 4; ++nt)
          acc[mt][nt] = __builtin_amdgcn_mfma_f32_16x16x32_bf16(
              af[mt], bf[nt], acc[mt][nt], 0, 0, 0);
    }
    __syncthreads();
  }
  // after this barrier all LDS reads are done -> safe to reuse As

  // ---- coalesced epilogue: per-wave 16x64 bf16 restage in As -------------
  unsigned short* wst = &As[wave * 1024];   // 16 rows x 64 cols ushort (2 KB)
  const int r0 = lane >> 2;                 // readback row 0..15
  const int k0c = lane & 3;                 // readback chunk base
#pragma unroll
  for (int mt = 0; mt < 4; ++mt) {
#pragma unroll
    for (int nt = 0; nt < 4; ++nt) {
#pragma unroll
      for (int i = 0; i < 4; ++i) {
        const int rr = quad * 4 + i;        // local row
        const int cc = nt * 16 + l15;       // local col
        wst[rr * 64 + (((cc >> 3) ^ (rr & 7)) << 3) + (cc & 7)] =
            rnbf(acc[mt][nt][i]);
      }
    }
    const int row_g = bm + wm * 64 + mt * 16 + r0;
#pragma unroll
    for (int kk = 0; kk < 2; ++kk) {
      const int k = k0c + kk * 4;           // chunk 0..7 (8 cols each)
      short8 v = *(const short8*)&wst[r0 * 64 + ((k ^ (r0 & 7)) << 3)];
      if (row_g < M)
        *(short8*)&C[(size_t)row_g * N + bn + wn * 64 + k * 8] = v;
    }
  }
}

// ====== fused independent preprocessing (cast fused into gemm1) =============
// blocks [0,512): hist of dst into cursor (atomic-bound)
// blocks [512,1024): W1 transpose-cast;  [1024,1152): W2 transpose-cast
#define PRE_HIST_B 512
#define PRE_W1_B 512
#define PRE_W2_B 128

__global__ __launch_bounds__(256) void pre_fused(
    const int* __restrict__ dst, int* __restrict__ cursor, int E,
    const float* __restrict__ W1, unsigned short* __restrict__ W1t,
    const float* __restrict__ W2, unsigned short* __restrict__ W2t) {
  __shared__ float tile[32][33];
  const int b = blockIdx.x, t = threadIdx.x;
  if (b < PRE_HIST_B) {
    for (int e = b * 256 + t; e < E; e += PRE_HIST_B * 256)
      atomicAdd(&cursor[dst[e]], 1);
  } else if (b < PRE_HIST_B + PRE_W1_B) {
    const int id = b - PRE_HIST_B;
    const int bx = (id & 15) * 32, by = (id >> 4) * 32;   // N=512, K=1024
    const int tx = t & 31, ty = t >> 5;
#pragma unroll
    for (int j = 0; j < 4; ++j)
      tile[ty + j * 8][tx] = W1[(size_t)(by + ty + j * 8) * 512 + bx + tx];
    __syncthreads();
#pragma unroll
    for (int j = 0; j < 4; ++j)
      W1t[(size_t)(bx + ty + j * 8) * 1024 + by + tx] = rnbf(tile[tx][ty + j * 8]);
  } else {
    const int id = b - (PRE_HIST_B + PRE_W1_B);
    const int bx = (id & 7) * 32, by = (id >> 3) * 32;    // N=256, K=512
    const int tx = t & 31, ty = t >> 5;
#pragma unroll
    for (int j = 0; j < 4; ++j)
      tile[ty + j * 8][tx] = W2[(size_t)(by + ty + j * 8) * 256 + bx + tx];
    __syncthreads();
#pragma unroll
    for (int j = 0; j < 4; ++j)
      W2t[(size_t)(bx + ty + j * 8) * 512 + by + tx] = rnbf(tile[tx][ty + j * 8]);
  }
}

// ====== parallel 3-phase scan ==============================================
__global__ __launch_bounds__(256) void scan_partial(
    const int* __restrict__ cursor, int* __restrict__ rowptr,
    int* __restrict__ partials, int n) {
  __shared__ int wsum[4];
  const int t = threadIdx.x, ln = t & 63, wv = t >> 6;
  const int base = blockIdx.x * 1024 + t * 4;
  int4 v = {0, 0, 0, 0};
  if (base + 3 < n) {
    v = *(const int4*)(cursor + base);
  } else {
    if (base + 0 < n) v.x = cursor[base + 0];
    if (base + 1 < n) v.y = cursor[base + 1];
    if (base + 2 < n) v.z = cursor[base + 2];
    if (base + 3 < n) v.w = cursor[base + 3];
  }
  const int s = v.x + v.y + v.z + v.w;
  int inc = s;
#pragma unroll
  for (int o = 1; o < 64; o <<= 1) {
    int y = __shfl_up(inc, o, 64);
    if (ln >= o) inc += y;
  }
  if (ln == 63) wsum[wv] = inc;
  __syncthreads();
  int wpre = 0;
#pragma unroll
  for (int k = 0; k < 4; ++k) wpre += (k < wv) ? wsum[k] : 0;
  const int exc = wpre + inc - s;          // block-local exclusive base
  if (base + 0 < n) rowptr[base + 1] = exc + v.x;
  if (base + 1 < n) rowptr[base + 2] = exc + v.x + v.y;
  if (base + 2 < n) rowptr[base + 3] = exc + v.x + v.y + v.z;
  if (base + 3 < n) rowptr[base + 4] = exc + s;
  if (t == 0) partials[blockIdx.x] = wsum[0] + wsum[1] + wsum[2] + wsum[3];
}

__global__ __launch_bounds__(64) void scan_base(int* partials, int nb) {
  const int t = threadIdx.x;
  const int v = (t < nb) ? partials[t] : 0;
  int inc = v;
#pragma unroll
  for (int o = 1; o < 64; o <<= 1) {
    int y = __shfl_up(inc, o, 64);
    if (t >= o) inc += y;
  }
  if (t < nb) partials[t] = inc - v;       // exclusive
}

__global__ __launch_bounds__(256) void scan_apply(
    int* cursor, int* __restrict__ rowptr, const int* __restrict__ partials,
    int n) {
  const int base = blockIdx.x * 1024 + threadIdx.x * 4;
  const int p = partials[blockIdx.x];
#pragma unroll
  for (int k = 0; k < 4; ++k) {
    const int i = base + k;
    if (i < n) {
      const int cnt = cursor[i];
      const int inc = p + rowptr[i + 1];
      rowptr[i + 1] = inc;
      cursor[i] = inc - cnt;
    }
  }
  if (blockIdx.x == 0 && threadIdx.x == 0) rowptr[0] = 0;
}

// ------- gather layer1: bf16 S [Nn,512] -> bf16 out (bias+relu fused) -------
__global__ __launch_bounds__(256) void gather1_b2b(
    const unsigned short* __restrict__ S, const int* __restrict__ es,
    const float* __restrict__ ws, const int* __restrict__ rowptr,
    const float* __restrict__ bias, unsigned short* __restrict__ out, int Nn) {
  const int tn = threadIdx.x & 63;                 // 64 thr/node, 8 bf16 each
  const int node = blockIdx.x * 4 + (threadIdx.x >> 6);
  if (node >= Nn) return;
  const int f = tn << 3;
  float acc[8] = {};
  const int beg = rowptr[node], end = rowptr[node + 1];
  for (int b = beg; b < end; b += 64) {
    const int m = end - b;
    int   sv_l = 0;
    float w_l  = 0.f;
    if (tn < m) { sv_l = es[b + tn]; w_l = ws[b + tn]; }
    const int cnt = (m < 64) ? m : 64;
#pragma unroll 2
    for (int i = 0; i < cnt; ++i) {
      const int   sv = __shfl(sv_l, i, 64);
      const float ww = __shfl(w_l, i, 64);
      const uint4 u = *(const uint4*)(S + (size_t)sv * 512 + f);
      acc[0] = fmaf(bflo(u.x), ww, acc[0]);
      acc[1] = fmaf(bfhi(u.x), ww, acc[1]);
      acc[2] = fmaf(bflo(u.y), ww, acc[2]);
      acc[3] = fmaf(bfhi(u.y), ww, acc[3]);
      acc[4] = fmaf(bflo(u.z), ww, acc[4]);
      acc[5] = fmaf(bfhi(u.z), ww, acc[5]);
      acc[6] = fmaf(bflo(u.w), ww, acc[6]);
      acc[7] = fmaf(bfhi(u.w), ww, acc[7]);
    }
  }
  float r[8];
#pragma unroll
  for (int j = 0; j < 8; ++j) r[j] = fmaxf(acc[j] + bias[f + j], 0.f);
  uint4 o;
  o.x = (unsigned int)rnbf(r[0]) | ((unsigned int)rnbf(r[1]) << 16);
  o.y = (unsigned int)rnbf(r[2]) | ((unsigned int)rnbf(r[3]) << 16);
  o.z = (unsigned int)rnbf(r[4]) | ((unsigned int)rnbf(r[5]) << 16);
  o.w = (unsigned int)rnbf(r[6]) | ((unsigned int)rnbf(r[7]) << 16);
  *(uint4*)(out + (size_t)node * 512 + f) = o;
}

// ------- gather layer2: bf16 S [Nn,256] -> f32 out (bias+relu fused) --------
__global__ __launch_bounds__(256) void gather2_b2f(
    const unsigned short* __restrict__ S, const int* __restrict__ es,
    const float* __restrict__ ws, const int* __restrict__ rowptr,
    const float* __restrict__ bias, float* __restrict__ out, int Nn) {
  const int tn = threadIdx.x & 31;                 // 32 thr/node, 8 bf16 each
  const int node = blockIdx.x * 8 + (threadIdx.x >> 5);
  if (node >= Nn) return;
  const int f = tn << 3;
  float acc[8] = {};
  const int beg = rowptr[node], end = rowptr[node + 1];
  for (int b = beg; b < end; b += 32) {
    const int m = end - b;
    int   sv_l = 0;
    float w_l  = 0.f;
    if (tn < m) { sv_l = es[b + tn]; w_l = ws[b + tn]; }
    const int cnt = (m < 32) ? m : 32;
#pragma unroll 2
    for (int i = 0; i < cnt; ++i) {
      const int   sv = __shfl(sv_l, i, 32);
      const float ww = __shfl(w_l, i, 32);
      const uint4 u = *(const uint4*)(S + (size_t)sv * 256 + f);
      acc[0] = fmaf(bflo(u.x), ww, acc[0]);
      acc[1] = fmaf(bfhi(u.x), ww, acc[1]);
      acc[2] = fmaf(bflo(u.y), ww, acc[2]);
      acc[3] = fmaf(bfhi(u.y), ww, acc[3]);
      acc[4] = fmaf(bflo(u.z), ww, acc[4]);
      acc[5] = fmaf(bfhi(u.z), ww, acc[5]);
      acc[6] = fmaf(bflo(u.w), ww, acc[6]);
      acc[7] = fmaf(bfhi(u.w), ww, acc[7]);
    }
  }
  float4 o1, o2;
  o1.x = fmaxf(acc[0] + bias[f + 0], 0.f);
  o1.y = fmaxf(acc[1] + bias[f + 1], 0.f);
  o1.z = fmaxf(acc[2] + bias[f + 2], 0.f);
  o1.w = fmaxf(acc[3] + bias[f + 3], 0.f);
  o2.x = fmaxf(acc[4] + bias[f + 4], 0.f);
  o2.y = fmaxf(acc[5] + bias[f + 5], 0.f);
  o2.z = fmaxf(acc[6] + bias[f + 6], 0.f);
  o2.w = fmaxf(acc[7] + bias[f + 7], 0.f);
  *(float4*)(out + (size_t)node * 256 + f) = o1;
  *(float4*)(out + (size_t)node * 256 + f + 4) = o2;
}

// ============================================================================
extern "C" void kernel_launch(void* const* d_in, const int* in_sizes, int n_in,
                              void* d_out, int out_size, void* d_ws, size_t ws_size,
                              hipStream_t stream) {
  const float* x  = (const float*)d_in[0];
  const int*   ei = (const int*)d_in[1];
  const float* ew = (const float*)d_in[2];
  const float* W1 = (const float*)d_in[3];
  const float* b1 = (const float*)d_in[4];
  const float* W2 = (const float*)d_in[5];
  const float* b2 = (const float*)d_in[6];

  const int D_IN = 1024, D_HID = 512, D_LAT = 256;
  const int Nn = in_sizes[0] / D_IN;   // 50000
  const int E  = in_sizes[2];          // 400000
  const int* src  = ei;
  const int* dstp = ei + E;

  // ws layout (region A holds hb; region B aliases s1->s2):
  //  A: [0, Nn*1024*2)            hb bf16 (x is read f32 directly by gemm1)
  //  B: [A, A + Nn*512*2)         s1 bf16; later s2 bf16
  //  C: W1t, W2t, rowptr, cursor, es, ws, partials         (~5 MB)
  char* base = (char*)d_ws;
  const size_t szA = (size_t)Nn * D_IN * 2;
  const size_t szB = (size_t)Nn * D_HID * 2;
  unsigned short* hb  = (unsigned short*)base;
  unsigned short* s1  = (unsigned short*)(base + szA);
  unsigned short* s2  = (unsigned short*)(base + szA);     // alias, s1 dead
  char* tail = base + szA + szB;
  unsigned short* W1t = (unsigned short*)tail;
  unsigned short* W2t = W1t + (size_t)D_IN * D_HID;
  int*   rowptr   = (int*)(W2t + (size_t)D_HID * D_LAT);
  int*   cursor   = rowptr + (Nn + 1);
  int*   es       = cursor + Nn;
  float* wsrt     = (float*)(es + E);
  int*   partials = (int*)(wsrt + E);

  const int nsb = (Nn + 1023) / 1024;   // 49 scan blocks (<= 64 for scan_base)

  // ---- preprocessing: memset -> fused{hist,transposes} -> scan3 ------------
  hipMemsetAsync(cursor, 0, (size_t)Nn * sizeof(int), stream);
  pre_fused<<<PRE_HIST_B + PRE_W1_B + PRE_W2_B, 256, 0, stream>>>(
      dstp, cursor, E, W1, W1t, W2, W2t);
  scan_partial<<<nsb, 256, 0, stream>>>(cursor, rowptr, partials, Nn);
  scan_base<<<1, 64, 0, stream>>>(partials, nsb);
  scan_apply<<<nsb, 256, 0, stream>>>(cursor, rowptr, partials, Nn);

  // ---- layer 1: gemm1 (A = f32 x, cast fused) + fill_csr trailing blocks ---
  const int gx1 = D_HID / TN;                 // 4
  const int gy1 = (Nn + TM - 1) / TM;         // 391
  const int ng1 = gx1 * gy1;
  const int nfill = 512;
  gemm_bf16_t<1><<<ng1 + nfill, 256, 0, stream>>>(
      (const void*)x, W1t, s1, Nn, D_HID, D_IN, gx1,
      dstp, src, ew, cursor, es, wsrt, E, ng1);
  gather1_b2b<<<(Nn + 3) / 4, 256, 0, stream>>>(
      s1, es, wsrt, rowptr, b1, hb, Nn);

  // ---- layer 2 ----
  const int gx2 = D_LAT / TN;                 // 2
  const int ng2 = gx2 * gy1;
  gemm_bf16_t<0><<<ng2, 256, 0, stream>>>(
      (const void*)hb, W2t, s2, Nn, D_LAT, D_HID, gx2,
      nullptr, nullptr, nullptr, nullptr, nullptr, nullptr, 0, ng2);
  gather2_b2f<<<(Nn + 7) / 8, 256, 0, stream>>>(
      s2, es, wsrt, rowptr, b2, (float*)d_out, Nn);
}